// Round 3
// baseline (1319.120 us; speedup 1.0000x reference)
//
#include <hip/hip_runtime.h>
#include <cstdint>
#include <cstddef>

// B=16, HW=4096, D=512, CL=768, K=512, V=512, NL=32, H=8.
// I/O FLOAT32. Internal big buffers bf16. ws ~214 MB.
// d_out hosting: [0,64MB)=visb bf16, [64,128MB)=xb bf16; both dead before mm GEMM writes f32.
// 9 dispatches: prep, gemm_fused3, simattv, langout_acc, gemmW, prod, gemm_mm, langW(+p2), langmm.

typedef __bf16 bf16x8 __attribute__((ext_vector_type(8)));
typedef float f32x4 __attribute__((ext_vector_type(4)));
typedef unsigned short ushort8 __attribute__((ext_vector_type(8)));
typedef unsigned short us4 __attribute__((ext_vector_type(4)));

__device__ __forceinline__ float bf2f(unsigned short u) {
  union { unsigned int i; float f; } c; c.i = ((unsigned int)u) << 16; return c.f;
}
__device__ __forceinline__ unsigned short f2bf(float f) {
  union { float f; unsigned int i; } c; c.f = f;
  unsigned int r = c.i + 0x7FFFu + ((c.i >> 16) & 1u);
  return (unsigned short)(r >> 16);
}
__device__ __forceinline__ float gelu_f(float x) {
  return 0.5f * x * (1.f + erff(x * 0.70710678118654752f));
}
__device__ __forceinline__ void gload16(const void* g, void* l) {
  __builtin_amdgcn_global_load_lds(
      (__attribute__((address_space(1))) unsigned int*)g,
      (__attribute__((address_space(3))) unsigned int*)l, 16, 0, 0);
}
// bijective XCD swizzle (m204): contiguous wgid chunk per XCD
__device__ __forceinline__ int xcd_swizzle(int orig, int nwg) {
  int qd = nwg >> 3, r = nwg & 7;
  int xcd = orig & 7, idx = orig >> 3;
  return (xcd < r ? xcd * (qd + 1) : r * (qd + 1) + (xcd - r) * qd) + idx;
}

// ---------------- workspace layout (bytes) ----------------
constexpr size_t OFF_SRQ  = 0;                                   // f32 [16][512][2] raw sum/sumsq
constexpr size_t OFF_SRLV = OFF_SRQ  + (size_t)16*512*2*4;       // f32 [16][768][2]
constexpr size_t OFF_SRW  = OFF_SRLV + (size_t)16*768*2*4;       // f32 [16][512][2]
constexpr size_t OFF_LACC = OFF_SRW  + (size_t)16*512*2*4;       // f32 [16][768][32]
constexpr size_t SZ_ZERO  = OFF_LACC + (size_t)16*768*32*4;      // zero [0, SZ_ZERO) each launch
constexpr size_t OFF_KBUF = SZ_ZERO;                             // f32 [16][512][32]
constexpr size_t OFF_VBUF = OFF_KBUF + (size_t)16*512*32*4;
constexpr size_t OFF_LANG = OFF_VBUF + (size_t)16*512*32*4;      // f32 [16][768][32]
constexpr size_t OFF_P2   = OFF_LANG + (size_t)16*768*32*4;      // f32 [16][768][32]
constexpr size_t OFF_PMX  = OFF_P2   + (size_t)16*768*32*4;      // f32 [32][128][32]
constexpr size_t OFF_PSM  = OFF_PMX  + (size_t)32*128*32*4;      // f32 [32][128][32]
constexpr size_t OFF_WB   = OFF_PSM  + (size_t)32*128*32*4;      // bf16 weights: vis|q|lv (cat [1792][512]), W, mm
constexpr size_t OFF_Q    = OFF_WB   + (size_t)1441792*2;        // bf16 q; reused: att@v out, then P
constexpr size_t OFF_LV   = OFF_Q    + (size_t)65536*512*2;      // bf16 lv; Wraw overlays after langout
constexpr size_t OFF_SIMB = OFF_LV   + (size_t)65536*768*2;      // bf16 sim (B,H,4096,32)

// ---------------- prep: f32->bf16 converts + small language convs + zero atomics region ----
// blocks [0,17088): cvt x + 5 weights ; [17088,20672): sconv langp/k/v ; [20672,21112): zero
__global__ __launch_bounds__(256) void prep_kernel(
    const float* __restrict__ x,
    const float* __restrict__ w_vis, const float* __restrict__ w_q,
    const float* __restrict__ w_lv, const float* __restrict__ w_W,
    const float* __restrict__ w_mm,
    unsigned short* __restrict__ xb, unsigned short* __restrict__ wb,
    const float* __restrict__ l,
    const float* __restrict__ w_langp, const float* __restrict__ b_langp,
    const float* __restrict__ w_k, const float* __restrict__ b_k,
    const float* __restrict__ w_v, const float* __restrict__ b_v,
    const float* __restrict__ lmask,
    float* __restrict__ lang, float* __restrict__ kbuf, float* __restrict__ vbuf,
    float* __restrict__ zbase)
{
  const int bid = blockIdx.x, t = threadIdx.x;
  if (bid < 17088) {
    int i = bid * 256 + t;
    if (i >= 4374528) return;
    const float* src;
    unsigned short* dst;
    if (i < 4194304) { src = x + (size_t)i * 8; dst = xb + (size_t)i * 8; }
    else {
      int j = i - 4194304;
      dst = wb + (size_t)j * 8;
      if (j < 32768)       src = w_vis + (size_t)j * 8;
      else if (j < 65536)  src = w_q  + (size_t)(j - 32768) * 8;
      else if (j < 114688) src = w_lv + (size_t)(j - 65536) * 8;
      else if (j < 147456) src = w_W  + (size_t)(j - 114688) * 8;
      else                 src = w_mm + (size_t)(j - 147456) * 8;
    }
    const f32x4* s = (const f32x4*)src;
    f32x4 a = s[0], b2 = s[1];
    ushort8 o;
#pragma unroll
    for (int j = 0; j < 4; ++j) { o[j] = f2bf(a[j]); o[j + 4] = f2bf(b2[j]); }
    *(ushort8*)dst = o;
  } else if (bid < 20672) {
    int sb = bid - 17088;
    int b = sb & 15, og = sb >> 4;          // og 0..223
    int ol = t >> 5, n = t & 31;
    const float* lb = l + (size_t)b * 768 * 32 + n;
    const float* wr;
    float bv;
    float* out;
    bool gel;
    if (og < 96) {
      int o = og * 8 + ol;
      wr = w_langp + (size_t)o * 768; bv = b_langp[o];
      out = &lang[((size_t)b * 768 + o) * 32 + n]; gel = true;
    } else if (og < 160) {
      int o = (og - 96) * 8 + ol;
      wr = w_k + (size_t)o * 768; bv = b_k[o];
      out = &kbuf[((size_t)b * 512 + o) * 32 + n]; gel = false;
    } else {
      int o = (og - 160) * 8 + ol;
      wr = w_v + (size_t)o * 768; bv = b_v[o];
      out = &vbuf[((size_t)b * 512 + o) * 32 + n]; gel = false;
    }
    float s = 0.f;
#pragma unroll 4
    for (int i = 0; i < 768; ++i) s += wr[i] * lb[(size_t)i * 32];
    s += bv;
    s = gel ? gelu_f(s) : s * lmask[b * 32 + n];
    *out = s;
  } else {
    size_t i = (size_t)(bid - 20672) * 256 + t;   // exactly 112640 f32x4 = 1802240 B
    const f32x4 z = {0.f, 0.f, 0.f, 0.f};
    ((f32x4*)zbase)[i] = z;
  }
}

// ---------------- big GEMM (m97 pattern): Y[m,n] = sum_k A[m,k]*Wb[n,k] + b[n] ----------------
template<bool GELU, bool STATS, bool OUTF32>
__global__ __launch_bounds__(256) void gemm_bt(
    const unsigned short* __restrict__ A, const unsigned short* __restrict__ Wb,
    const float* __restrict__ bias, void* __restrict__ Yout,
    float* __restrict__ statsraw, int N, int Kd, int nbn)
{
  __shared__ __align__(16) unsigned short As[128 * 64];
  __shared__ __align__(16) unsigned short Bs[128 * 64];
  const int t = threadIdx.x;
  const int wave = t >> 6, lane = t & 63;
  const int ln = lane & 15, quad = lane >> 4;
  const int wgid = xcd_swizzle(blockIdx.x, gridDim.x);
  const int mt = wgid / nbn, nt = wgid - mt * nbn;
  const int m0 = mt * 128, n0 = nt * 128;
  const int wm = (wave >> 1) * 64, wn = (wave & 1) * 64;
  const f32x4 fzero = {0.f, 0.f, 0.f, 0.f};
  f32x4 acc[4][4];
#pragma unroll
  for (int i = 0; i < 4; ++i)
#pragma unroll
    for (int j = 0; j < 4; ++j) acc[i][j] = fzero;
  const int lrow = lane >> 3;
  const int lch  = lane & 7;

  for (int k0 = 0; k0 < Kd; k0 += 64) {
#pragma unroll
    for (int it = 0; it < 4; ++it) {
      int g = wave * 4 + it;
      int row = g * 8 + lrow;
      gload16(A  + (size_t)(m0 + row) * Kd + k0 + lch * 8, &As[g * 512]);
      gload16(Wb + (size_t)(n0 + row) * Kd + k0 + lch * 8, &Bs[g * 512]);
    }
    __syncthreads();
#pragma unroll
    for (int kk = 0; kk < 64; kk += 32) {
      int c = (kk >> 3) + quad;
      bf16x8 af[4], bfr[4];
#pragma unroll
      for (int i = 0; i < 4; ++i)
        af[i] = *(const bf16x8*)&As[(wm + i * 16 + ln) * 64 + c * 8];
#pragma unroll
      for (int j = 0; j < 4; ++j)
        bfr[j] = *(const bf16x8*)&Bs[(wn + j * 16 + ln) * 64 + c * 8];
#pragma unroll
      for (int i = 0; i < 4; ++i)
#pragma unroll
        for (int j = 0; j < 4; ++j)
          acc[i][j] = __builtin_amdgcn_mfma_f32_16x16x32_bf16(af[i], bfr[j], acc[i][j], 0, 0, 0);
    }
    __syncthreads();
  }
  float bb[4];
#pragma unroll
  for (int j = 0; j < 4; ++j) bb[j] = bias[n0 + wn + j * 16 + ln];
#pragma unroll
  for (int i = 0; i < 4; ++i)
#pragma unroll
    for (int j = 0; j < 4; ++j)
#pragma unroll
      for (int r = 0; r < 4; ++r) {
        float v = acc[i][j][r] + bb[j];
        if (GELU) v = gelu_f(v);
        acc[i][j][r] = v;
        size_t row = (size_t)(m0 + wm + i * 16 + quad * 4 + r);
        size_t idx = row * N + (n0 + wn + j * 16 + ln);
        if (OUTF32) ((float*)Yout)[idx] = v;
        else ((unsigned short*)Yout)[idx] = f2bf(v);
      }
  if (STATS) {
    float* cs = (float*)As;
    cs[t] = 0.f;
    __syncthreads();
#pragma unroll
    for (int j = 0; j < 4; ++j) {
      float s = 0.f, s2 = 0.f;
#pragma unroll
      for (int i = 0; i < 4; ++i)
#pragma unroll
        for (int r = 0; r < 4; ++r) { float v = acc[i][j][r]; s += v; s2 += v * v; }
      // wave-level pre-reduce across quads (4x fewer LDS atomics)
      s  += __shfl_xor(s, 16);  s  += __shfl_xor(s, 32);
      s2 += __shfl_xor(s2, 16); s2 += __shfl_xor(s2, 32);
      if (quad == 0) {
        int cl = wn + j * 16 + ln;
        atomicAdd(&cs[cl], s);
        atomicAdd(&cs[128 + cl], s2);
      }
    }
    __syncthreads();
    int bIdx = m0 >> 12;
    if (t < 128) atomicAdd(&statsraw[((size_t)bIdx * N + n0 + t) * 2], cs[t]);
    else atomicAdd(&statsraw[((size_t)bIdx * N + n0 + (t - 128)) * 2 + 1], cs[t]);
  }
}

// ---------------- fused vis|q|lv GEMM: Ncat=1792 over concat weights, A read once ----------------
__global__ __launch_bounds__(256) void gemm_fused3(
    const unsigned short* __restrict__ A, const unsigned short* __restrict__ Wcat,
    const float* __restrict__ b_vis, const float* __restrict__ b_q, const float* __restrict__ b_lv,
    unsigned short* __restrict__ visb, unsigned short* __restrict__ qout,
    unsigned short* __restrict__ lvout, float* __restrict__ srq, float* __restrict__ srlv)
{
  constexpr int NBN = 14, Kd = 512;
  __shared__ __align__(16) unsigned short As[128 * 64];
  __shared__ __align__(16) unsigned short Bs[128 * 64];
  const int t = threadIdx.x;
  const int wave = t >> 6, lane = t & 63;
  const int ln = lane & 15, quad = lane >> 4;
  const int wgid = xcd_swizzle(blockIdx.x, gridDim.x);
  const int mt = wgid / NBN, nt = wgid - mt * NBN;
  const int m0 = mt * 128, n0 = nt * 128;
  const int wm = (wave >> 1) * 64, wn = (wave & 1) * 64;
  const f32x4 fzero = {0.f, 0.f, 0.f, 0.f};
  f32x4 acc[4][4];
#pragma unroll
  for (int i = 0; i < 4; ++i)
#pragma unroll
    for (int j = 0; j < 4; ++j) acc[i][j] = fzero;
  const int lrow = lane >> 3;
  const int lch  = lane & 7;

  for (int k0 = 0; k0 < Kd; k0 += 64) {
#pragma unroll
    for (int it = 0; it < 4; ++it) {
      int g = wave * 4 + it;
      int row = g * 8 + lrow;
      gload16(A    + (size_t)(m0 + row) * Kd + k0 + lch * 8, &As[g * 512]);
      gload16(Wcat + (size_t)(n0 + row) * Kd + k0 + lch * 8, &Bs[g * 512]);
    }
    __syncthreads();
#pragma unroll
    for (int kk = 0; kk < 64; kk += 32) {
      int c = (kk >> 3) + quad;
      bf16x8 af[4], bfr[4];
#pragma unroll
      for (int i = 0; i < 4; ++i)
        af[i] = *(const bf16x8*)&As[(wm + i * 16 + ln) * 64 + c * 8];
#pragma unroll
      for (int j = 0; j < 4; ++j)
        bfr[j] = *(const bf16x8*)&Bs[(wn + j * 16 + ln) * 64 + c * 8];
#pragma unroll
      for (int i = 0; i < 4; ++i)
#pragma unroll
        for (int j = 0; j < 4; ++j)
          acc[i][j] = __builtin_amdgcn_mfma_f32_16x16x32_bf16(af[i], bfr[j], acc[i][j], 0, 0, 0);
    }
    __syncthreads();
  }
  int seg = (nt < 4) ? 0 : (nt < 8 ? 1 : 2);
  const float* bias = (seg == 0) ? b_vis : (seg == 1 ? b_q : b_lv);
  unsigned short* Y = (seg == 0) ? visb : (seg == 1 ? qout : lvout);
  float* statsraw   = (seg == 1) ? srq : srlv;
  const int nbase   = n0 - ((seg == 0) ? 0 : (seg == 1 ? 512 : 1024));
  const int Nseg    = (seg == 2) ? 768 : 512;

  float bb[4];
#pragma unroll
  for (int j = 0; j < 4; ++j) bb[j] = bias[nbase + wn + j * 16 + ln];
#pragma unroll
  for (int i = 0; i < 4; ++i)
#pragma unroll
    for (int j = 0; j < 4; ++j)
#pragma unroll
      for (int r = 0; r < 4; ++r) {
        float v = acc[i][j][r] + bb[j];
        if (seg == 0) v = gelu_f(v);
        acc[i][j][r] = v;
        size_t row = (size_t)(m0 + wm + i * 16 + quad * 4 + r);
        Y[row * Nseg + (nbase + wn + j * 16 + ln)] = f2bf(v);
      }
  if (seg != 0) {
    float* cs = (float*)As;
    cs[t] = 0.f;
    __syncthreads();
#pragma unroll
    for (int j = 0; j < 4; ++j) {
      float s = 0.f, s2 = 0.f;
#pragma unroll
      for (int i = 0; i < 4; ++i)
#pragma unroll
        for (int r = 0; r < 4; ++r) { float v = acc[i][j][r]; s += v; s2 += v * v; }
      s  += __shfl_xor(s, 16);  s  += __shfl_xor(s, 32);
      s2 += __shfl_xor(s2, 16); s2 += __shfl_xor(s2, 32);
      if (quad == 0) {
        int cl = wn + j * 16 + ln;
        atomicAdd(&cs[cl], s);
        atomicAdd(&cs[128 + cl], s2);
      }
    }
    __syncthreads();
    int bIdx = m0 >> 12;
    if (t < 128) atomicAdd(&statsraw[((size_t)bIdx * Nseg + nbase + t) * 2], cs[t]);
    else atomicAdd(&statsraw[((size_t)bIdx * Nseg + nbase + (t - 128)) * 2 + 1], cs[t]);
  }
}

// ---------------- fused sim + att-softmax + att@v + latt partial stats (MFMA) ----------------
// q-InstanceNorm folded into k. Stats computed inline from raw srq sums.
__global__ __launch_bounds__(256) void simattv_kernel(
    const unsigned short* __restrict__ qraw, const float* __restrict__ srq,
    const float* __restrict__ kbuf, const float* __restrict__ vbuf,
    const float* __restrict__ lmask,
    unsigned short* __restrict__ simb, unsigned short* __restrict__ outb,
    float* __restrict__ pmx, float* __restrict__ psm)
{
  __shared__ __align__(16) unsigned short kThi[32][72];
  __shared__ __align__(16) unsigned short kTlo[32][72];
  __shared__ __align__(16) unsigned short vshi[64][40];
  __shared__ __align__(16) unsigned short vslo[64][40];
  __shared__ __align__(16) unsigned short pq[4][32][40];
  __shared__ float sm[64], srs[64], cb[32];
  __shared__ float wmax[4][32], wsum[4][32];

  const int qc = blockIdx.x, q0 = qc * 128, h = blockIdx.y, b = blockIdx.z;
  const int bh = b * 8 + h;
  const int t = threadIdx.x;
  const int wv = t >> 6, lane = t & 63, ln = lane & 15, quad = lane >> 4;
  const float scale = 0.04419417382415922f;  // 512^-0.5

  if (t < 64) {
    float s  = srq[(b * 512 + h * 64 + t) * 2];
    float s2 = srq[(b * 512 + h * 64 + t) * 2 + 1];
    float mean = s * (1.f / 4096.f);
    float var  = fmaxf(s2 * (1.f / 4096.f) - mean * mean, 0.f);
    sm[t]  = mean;
    srs[t] = rsqrtf(var + 1e-5f) * scale;
  }
  __syncthreads();

  const float* kb = kbuf + ((size_t)b * 512 + h * 64) * 32;
  const float* vb = vbuf + ((size_t)b * 512 + h * 64) * 32;
  for (int e = t; e < 2048; e += 256) {
    int d = e >> 5, n = e & 31;
    float kv = kb[e] * srs[d];
    unsigned short khi = f2bf(kv);
    kThi[n][d] = khi;
    kTlo[n][d] = f2bf(kv - bf2f(khi));
    float vv = vb[e];
    unsigned short vhi = f2bf(vv);
    vshi[d][n] = vhi;
    vslo[d][n] = f2bf(vv - bf2f(vhi));
  }
  if (t < 32) {
    float s = 0.f;
#pragma unroll 8
    for (int d = 0; d < 64; ++d) s += sm[d] * srs[d] * kb[d * 32 + t];
    cb[t] = 10000.f * (lmask[b * 32 + t] - 1.f) - s;
  }

  const unsigned short* qbase = qraw + ((size_t)(b * 4096) + q0 + wv * 32) * 512 + h * 64;
  bf16x8 qfr[2][2];
#pragma unroll
  for (int qf = 0; qf < 2; ++qf)
#pragma unroll
    for (int kf = 0; kf < 2; ++kf)
      qfr[qf][kf] = *(const bf16x8*)(qbase + (size_t)(qf * 16 + ln) * 512 + kf * 32 + quad * 8);
  __syncthreads();

  const f32x4 fz = {0.f, 0.f, 0.f, 0.f};
  f32x4 accS[2][2] = {{fz, fz}, {fz, fz}};
#pragma unroll
  for (int kf = 0; kf < 2; ++kf) {
#pragma unroll
    for (int nf = 0; nf < 2; ++nf) {
      bf16x8 kh = *(const bf16x8*)&kThi[nf * 16 + ln][kf * 32 + quad * 8];
      bf16x8 kl = *(const bf16x8*)&kTlo[nf * 16 + ln][kf * 32 + quad * 8];
#pragma unroll
      for (int qf = 0; qf < 2; ++qf) {
        accS[qf][nf] = __builtin_amdgcn_mfma_f32_16x16x32_bf16(qfr[qf][kf], kh, accS[qf][nf], 0, 0, 0);
        accS[qf][nf] = __builtin_amdgcn_mfma_f32_16x16x32_bf16(qfr[qf][kf], kl, accS[qf][nf], 0, 0, 0);
      }
    }
  }
  float cb0 = cb[ln], cb1 = cb[16 + ln];
#pragma unroll
  for (int qf = 0; qf < 2; ++qf)
#pragma unroll
    for (int r = 0; r < 4; ++r) {
      accS[qf][0][r] += cb0;
      accS[qf][1][r] += cb1;
    }
  {
    unsigned short* sgb = simb + ((size_t)bh * 4096 + q0 + wv * 32) * 32;
#pragma unroll
    for (int qf = 0; qf < 2; ++qf)
#pragma unroll
      for (int r = 0; r < 4; ++r) {
        size_t rowo = (size_t)(qf * 16 + quad * 4 + r) * 32;
        sgb[rowo + ln]      = f2bf(accS[qf][0][r]);
        sgb[rowo + 16 + ln] = f2bf(accS[qf][1][r]);
      }
  }
#pragma unroll
  for (int nf = 0; nf < 2; ++nf) {
    float m = accS[0][nf][0];
#pragma unroll
    for (int r = 1; r < 4; ++r) m = fmaxf(m, accS[0][nf][r]);
#pragma unroll
    for (int r = 0; r < 4; ++r) m = fmaxf(m, accS[1][nf][r]);
    m = fmaxf(m, __shfl_xor(m, 16));
    m = fmaxf(m, __shfl_xor(m, 32));
    float s = 0.f;
#pragma unroll
    for (int qf = 0; qf < 2; ++qf)
#pragma unroll
      for (int r = 0; r < 4; ++r) s += __expf(accS[qf][nf][r] - m);
    s += __shfl_xor(s, 16);
    s += __shfl_xor(s, 32);
    if (quad == 0) { wmax[wv][nf * 16 + ln] = m; wsum[wv][nf * 16 + ln] = s; }
  }
#pragma unroll
  for (int qf = 0; qf < 2; ++qf) {
#pragma unroll
    for (int r = 0; r < 4; ++r) {
      float a0 = accS[qf][0][r], a1 = accS[qf][1][r];
      float m = fmaxf(a0, a1);
      m = fmaxf(m, __shfl_xor(m, 1));
      m = fmaxf(m, __shfl_xor(m, 2));
      m = fmaxf(m, __shfl_xor(m, 4));
      m = fmaxf(m, __shfl_xor(m, 8));
      float e0 = __expf(a0 - m), e1 = __expf(a1 - m);
      float s = e0 + e1;
      s += __shfl_xor(s, 1);
      s += __shfl_xor(s, 2);
      s += __shfl_xor(s, 4);
      s += __shfl_xor(s, 8);
      float inv = 1.f / s;
      int row = qf * 16 + quad * 4 + r;
      pq[wv][row][ln]      = f2bf(e0 * inv);
      pq[wv][row][16 + ln] = f2bf(e1 * inv);
    }
  }
  __syncthreads();
  bf16x8 vfh[4], vfl[4];
#pragma unroll
  for (int mf = 0; mf < 4; ++mf) {
    vfh[mf] = *(const bf16x8*)&vshi[mf * 16 + ln][quad * 8];
    vfl[mf] = *(const bf16x8*)&vslo[mf * 16 + ln][quad * 8];
  }
#pragma unroll
  for (int nf = 0; nf < 2; ++nf) {
    bf16x8 pb = *(const bf16x8*)&pq[wv][nf * 16 + ln][quad * 8];
    f32x4 accO[4] = {fz, fz, fz, fz};
#pragma unroll
    for (int mf = 0; mf < 4; ++mf) {
      accO[mf] = __builtin_amdgcn_mfma_f32_16x16x32_bf16(vfh[mf], pb, accO[mf], 0, 0, 0);
      accO[mf] = __builtin_amdgcn_mfma_f32_16x16x32_bf16(vfl[mf], pb, accO[mf], 0, 0, 0);
    }
    unsigned short* op = outb + ((size_t)(b * 4096) + q0 + wv * 32 + nf * 16 + ln) * 512 + h * 64;
#pragma unroll
    for (int mf = 0; mf < 4; ++mf) {
      us4 o;
#pragma unroll
      for (int r = 0; r < 4; ++r) o[r] = f2bf(accO[mf][r]);
      *(us4*)(op + mf * 16 + quad * 4) = o;
    }
  }
  __syncthreads();
  if (t < 32) {
    float M = wmax[0][t], S = wsum[0][t];
#pragma unroll
    for (int g = 1; g < 4; ++g) {
      float m2 = wmax[g][t], s2 = wsum[g][t];
      if (m2 > M) { S = S * __expf(M - m2) + s2; M = m2; }
      else S += s2 * __expf(m2 - M);
    }
    pmx[((size_t)qc * 128 + bh) * 32 + t] = M;
    psm[((size_t)qc * 128 + bh) * 32 + t] = S;
  }
}

// ---------------- lang_out[b,h,c,n] += sum_q latt[n,q]*lvnorm[c,q] ----------------
// latt stats merged inline from pmx/psm; lv-norm stats inline from srlv.
__global__ __launch_bounds__(256) void langout_acc_kernel(
    const unsigned short* __restrict__ simb, const float* __restrict__ pmx,
    const float* __restrict__ psm, const unsigned short* __restrict__ lvraw,
    const float* __restrict__ srlv, float* __restrict__ lacc)
{
  __shared__ __align__(16) float pt[64][32];
  __shared__ __align__(16) float lvt[64][96];
  __shared__ float cm[96], cr[96], lm[32], li[32];
  int bh = blockIdx.x, b = bh >> 3, h = bh & 7;
  int qs0 = blockIdx.y * 512;
  int t = threadIdx.x;
  if (t < 96) {
    float s  = srlv[(b * 768 + h * 96 + t) * 2];
    float s2 = srlv[(b * 768 + h * 96 + t) * 2 + 1];
    float mean = s * (1.f / 4096.f);
    float var  = fmaxf(s2 * (1.f / 4096.f) - mean * mean, 0.f);
    cm[t] = mean;
    cr[t] = rsqrtf(var + 1e-5f);
  } else if (t >= 128 && t < 160) {
    int n = t - 128;
    float M = -1e30f, S = 0.f;
#pragma unroll 4
    for (int c = 0; c < 32; ++c) {
      float m2 = pmx[((size_t)c * 128 + bh) * 32 + n];
      float s2 = psm[((size_t)c * 128 + bh) * 32 + n];
      if (m2 > M) { S = S * __expf(M - m2) + s2; M = m2; }
      else S += s2 * __expf(m2 - M);
    }
    lm[n] = M;
    li[n] = 1.f / S;
  }
  __syncthreads();
  int n = t & 31, cg = t >> 5;
  float acc[12];
#pragma unroll
  for (int r = 0; r < 12; ++r) acc[r] = 0.f;
  for (int c0 = 0; c0 < 512; c0 += 64) {
    if (c0) __syncthreads();
#pragma unroll
    for (int i = 0; i < 8; ++i) {
      int e = t + 256 * i;
      int ql = e >> 5, nn = e & 31;
      float x = bf2f(simb[((size_t)bh * 4096 + qs0 + c0 + ql) * 32 + nn]);
      pt[ql][nn] = __expf(x - lm[nn]) * li[nn];
    }
#pragma unroll
    for (int i = 0; i < 24; ++i) {
      int e = t + 256 * i;
      int ql = e / 96, cc = e % 96;
      float v = bf2f(lvraw[((size_t)(b * 4096) + qs0 + c0 + ql) * 768 + h * 96 + cc]);
      lvt[ql][cc] = (v - cm[cc]) * cr[cc];
    }
    __syncthreads();
    for (int q = 0; q < 64; ++q) {
      float pv = pt[q][n];
      const f32x4* lp = (const f32x4*)&lvt[q][cg * 12];
      f32x4 a0 = lp[0], a1 = lp[1], a2 = lp[2];
      acc[0] += pv * a0[0]; acc[1] += pv * a0[1]; acc[2]  += pv * a0[2]; acc[3]  += pv * a0[3];
      acc[4] += pv * a1[0]; acc[5] += pv * a1[1]; acc[6]  += pv * a1[2]; acc[7]  += pv * a1[3];
      acc[8] += pv * a2[0]; acc[9] += pv * a2[1]; acc[10] += pv * a2[2]; acc[11] += pv * a2[3];
    }
  }
#pragma unroll
  for (int r = 0; r < 12; ++r)
    atomicAdd(&lacc[((size_t)b * 768 + h * 96 + cg * 12 + r) * 32 + n], acc[r]);
}

// ---------------- P = vis * inorm(Wout), stats inline from srw ----------------
__global__ __launch_bounds__(256) void prod_kernel(
    const unsigned short* __restrict__ visb, const unsigned short* __restrict__ wraw,
    const float* __restrict__ srw, unsigned short* __restrict__ P)
{
  size_t idx = ((size_t)blockIdx.x * 256 + threadIdx.x) * 8;
  int b = (int)(idx >> 21);
  int c = (int)(idx & 511);
  ushort8 vv = *(const ushort8*)&visb[idx];
  ushort8 wv = *(const ushort8*)&wraw[idx];
  ushort8 pv;
#pragma unroll
  for (int i = 0; i < 8; ++i) {
    float s  = srw[(b * 512 + c + i) * 2];
    float s2 = srw[(b * 512 + c + i) * 2 + 1];
    float mean = s * (1.f / 4096.f);
    float var  = fmaxf(s2 * (1.f / 4096.f) - mean * mean, 0.f);
    float rs   = rsqrtf(var + 1e-5f);
    pv[i] = f2bf(bf2f(vv[i]) * ((bf2f(wv[i]) - mean) * rs));
  }
  *(ushort8*)&P[idx] = pv;
}

// ---------------- langW conv + inorm over NL + *lang fuse (writes p2 directly) ----------------
__global__ __launch_bounds__(256) void langW_kernel(
    const float* __restrict__ lacc, const float* __restrict__ w,
    const float* __restrict__ bias, const float* __restrict__ lmask,
    const float* __restrict__ lang, float* __restrict__ p2)
{
  int b = blockIdx.x, og = blockIdx.y;
  int ol = threadIdx.x >> 5, n = threadIdx.x & 31;
  int o = og * 8 + ol;
  const float* ab = lacc + (size_t)b * 768 * 32 + n;
  const float* wr = w + (size_t)o * 768;
  float s = 0.f;
#pragma unroll 4
  for (int i = 0; i < 768; ++i) s += wr[i] * ab[(size_t)i * 32];
  float y = s * lmask[b * 32 + n] + bias[o];
  float m = y;
#pragma unroll
  for (int off = 16; off >= 1; off >>= 1) m += __shfl_xor(m, off);
  m *= (1.f / 32.f);
  float d = y - m;
  float vv = d * d;
#pragma unroll
  for (int off = 16; off >= 1; off >>= 1) vv += __shfl_xor(vv, off);
  vv *= (1.f / 32.f);
  size_t idx = ((size_t)b * 768 + o) * 32 + n;
  p2[idx] = lang[idx] * (d * rsqrtf(vv + 1e-5f));
}

// ---------------- langmm conv + gelu, store transposed (B,NL,CL) f32 ----------------
__global__ __launch_bounds__(256) void langmm_kernel(
    const float* __restrict__ p2, const float* __restrict__ w,
    const float* __restrict__ bias, float* __restrict__ out1)
{
  int b = blockIdx.x, og = blockIdx.y;
  int ol = threadIdx.x >> 5, n = threadIdx.x & 31;
  int o = og * 8 + ol;
  const float* pb = p2 + (size_t)b * 768 * 32 + n;
  const float* wr = w + (size_t)o * 768;
  float s = 0.f;
#pragma unroll 4
  for (int i = 0; i < 768; ++i) s += wr[i] * pb[(size_t)i * 32];
  s = gelu_f(s + bias[o]);
  __shared__ float tile[8][32];
  tile[ol][n] = s;
  __syncthreads();
  int nn = threadIdx.x >> 3, cl = threadIdx.x & 7;
  out1[((size_t)b * 32 + nn) * 768 + og * 8 + cl] = tile[cl][nn];
}

// ---------------- launch ----------------
extern "C" void kernel_launch(void* const* d_in, const int* in_sizes, int n_in,
                              void* d_out, int out_size, void* d_ws, size_t ws_size,
                              hipStream_t stream)
{
  (void)in_sizes; (void)n_in; (void)out_size; (void)ws_size;
  const float* x       = (const float*)d_in[0];
  const float* l       = (const float*)d_in[1];
  const float* lmask   = (const float*)d_in[2];
  const float* w_vis   = (const float*)d_in[3];
  const float* b_vis   = (const float*)d_in[4];
  const float* w_langp = (const float*)d_in[5];
  const float* b_langp = (const float*)d_in[6];
  const float* w_q     = (const float*)d_in[7];
  const float* b_q     = (const float*)d_in[8];
  const float* w_k     = (const float*)d_in[9];
  const float* b_k     = (const float*)d_in[10];
  const float* w_v     = (const float*)d_in[11];
  const float* b_v     = (const float*)d_in[12];
  const float* w_lv    = (const float*)d_in[13];
  const float* b_lv    = (const float*)d_in[14];
  const float* w_W     = (const float*)d_in[15];
  const float* b_W     = (const float*)d_in[16];
  const float* w_langW = (const float*)d_in[17];
  const float* b_langW = (const float*)d_in[18];
  const float* w_mm    = (const float*)d_in[19];
  const float* b_mm    = (const float*)d_in[20];
  const float* w_langmm= (const float*)d_in[21];
  const float* b_langmm= (const float*)d_in[22];

  char* ws = (char*)d_ws;
  float* srq  = (float*)(ws + OFF_SRQ);
  float* srlv = (float*)(ws + OFF_SRLV);
  float* srw  = (float*)(ws + OFF_SRW);
  float* lacc = (float*)(ws + OFF_LACC);
  float* kbuf = (float*)(ws + OFF_KBUF);
  float* vbuf = (float*)(ws + OFF_VBUF);
  float* lang = (float*)(ws + OFF_LANG);
  float* p2   = (float*)(ws + OFF_P2);
  float* pmx  = (float*)(ws + OFF_PMX);
  float* psm  = (float*)(ws + OFF_PSM);
  unsigned short* wb    = (unsigned short*)(ws + OFF_WB);
  unsigned short* wbW   = wb + 917504;
  unsigned short* wbmm  = wb + 1179648;
  unsigned short* qraw  = (unsigned short*)(ws + OFF_Q);
  unsigned short* lvraw = (unsigned short*)(ws + OFF_LV);
  unsigned short* wraw  = (unsigned short*)(ws + OFF_LV);
  unsigned short* simb  = (unsigned short*)(ws + OFF_SIMB);
  float* out0 = (float*)d_out;
  float* out1 = out0 + (size_t)16 * 4096 * 512;
  unsigned short* visb = (unsigned short*)d_out;                 // [0,64MB)
  unsigned short* xb   = (unsigned short*)d_out + 33554432;      // [64,128MB)

  // prep: converts + small convs + zero of atomic accumulators
  prep_kernel<<<21112, 256, 0, stream>>>(x, w_vis, w_q, w_lv, w_W, w_mm, xb, wb,
                                         l, w_langp, b_langp, w_k, b_k, w_v, b_v,
                                         lmask, lang, kbuf, vbuf, (float*)ws);

  // fused vis|q|lv GEMM: A (xb) read once, n-fastest + XCD swizzle
  gemm_fused3<<<512 * 14, 256, 0, stream>>>(xb, wb, b_vis, b_q, b_lv,
                                            visb, qraw, lvraw, srq, srlv);

  // attention (fused sim+softmax+PV+latt partials, MFMA; q-norm stats inline)
  simattv_kernel<<<dim3(32, 8, 16), 256, 0, stream>>>(qraw, srq, kbuf, vbuf, lmask, simb, qraw, pmx, psm);
  langout_acc_kernel<<<dim3(128, 8), 256, 0, stream>>>(simb, pmx, psm, lvraw, srlv, lacc);

  // visual output path
  gemm_bt<false, true,  false><<<512 * 4, 256, 0, stream>>>(qraw, wbW, b_W, wraw, srw, 512, 512, 4);
  prod_kernel<<<16384, 256, 0, stream>>>(visb, wraw, srw, qraw);
  gemm_bt<true,  false, true ><<<512 * 4, 256, 0, stream>>>(qraw, wbmm, b_mm, out0, nullptr, 512, 512, 4);

  // language output path
  langW_kernel<<<dim3(16, 96), 256, 0, stream>>>(lacc, w_langW, b_langW, lmask, lang, p2);
  langmm_kernel<<<dim3(16, 96), 256, 0, stream>>>(p2, w_langmm, b_langmm, out1);
}

// Round 4
// 1215.520 us; speedup vs baseline: 1.0852x; 1.0852x over previous
//
#include <hip/hip_runtime.h>
#include <cstdint>
#include <cstddef>

// B=16, HW=4096, D=512, CL=768, K=512, V=512, NL=32, H=8.
// I/O FLOAT32. Internal big buffers bf16. ws ~214 MB.
// d_out hosting: [0,64MB)=visb bf16, [64,128MB)=xb bf16; both dead before mm GEMM writes f32.
// 9 dispatches: prep, gemm_fused3, simattv, langout_acc, gemmW, prod, gemm_mm, langW(+p2), langmm.
// GEMMs: 128x128 tile, BK=64, explicit double-buffered LDS, prefetch-before-compute,
// ONE __syncthreads per K-step (T3 minimum-2-phase; vmcnt drain overlapped with MFMA).

typedef __bf16 bf16x8 __attribute__((ext_vector_type(8)));
typedef float f32x4 __attribute__((ext_vector_type(4)));
typedef unsigned short ushort8 __attribute__((ext_vector_type(8)));
typedef unsigned short us4 __attribute__((ext_vector_type(4)));

__device__ __forceinline__ float bf2f(unsigned short u) {
  union { unsigned int i; float f; } c; c.i = ((unsigned int)u) << 16; return c.f;
}
__device__ __forceinline__ unsigned short f2bf(float f) {
  union { float f; unsigned int i; } c; c.f = f;
  unsigned int r = c.i + 0x7FFFu + ((c.i >> 16) & 1u);
  return (unsigned short)(r >> 16);
}
__device__ __forceinline__ float gelu_f(float x) {
  return 0.5f * x * (1.f + erff(x * 0.70710678118654752f));
}
__device__ __forceinline__ void gload16(const void* g, void* l) {
  __builtin_amdgcn_global_load_lds(
      (__attribute__((address_space(1))) unsigned int*)g,
      (__attribute__((address_space(3))) unsigned int*)l, 16, 0, 0);
}
// bijective XCD swizzle (m204): contiguous wgid chunk per XCD
__device__ __forceinline__ int xcd_swizzle(int orig, int nwg) {
  int qd = nwg >> 3, r = nwg & 7;
  int xcd = orig & 7, idx = orig >> 3;
  return (xcd < r ? xcd * (qd + 1) : r * (qd + 1) + (xcd - r) * qd) + idx;
}

// ---------------- workspace layout (bytes) ----------------
constexpr size_t OFF_SRQ  = 0;                                   // f32 [16][512][2] raw sum/sumsq
constexpr size_t OFF_SRLV = OFF_SRQ  + (size_t)16*512*2*4;       // f32 [16][768][2]
constexpr size_t OFF_SRW  = OFF_SRLV + (size_t)16*768*2*4;       // f32 [16][512][2]
constexpr size_t OFF_LACC = OFF_SRW  + (size_t)16*512*2*4;       // f32 [16][768][32]
constexpr size_t SZ_ZERO  = OFF_LACC + (size_t)16*768*32*4;      // zero [0, SZ_ZERO) each launch
constexpr size_t OFF_KBUF = SZ_ZERO;                             // f32 [16][512][32]
constexpr size_t OFF_VBUF = OFF_KBUF + (size_t)16*512*32*4;
constexpr size_t OFF_LANG = OFF_VBUF + (size_t)16*512*32*4;      // f32 [16][768][32]
constexpr size_t OFF_P2   = OFF_LANG + (size_t)16*768*32*4;      // f32 [16][768][32]
constexpr size_t OFF_PMX  = OFF_P2   + (size_t)16*768*32*4;      // f32 [32][128][32]
constexpr size_t OFF_PSM  = OFF_PMX  + (size_t)32*128*32*4;      // f32 [32][128][32]
constexpr size_t OFF_WB   = OFF_PSM  + (size_t)32*128*32*4;      // bf16 weights: vis|q|lv (cat [1792][512]), W, mm
constexpr size_t OFF_Q    = OFF_WB   + (size_t)1441792*2;        // bf16 q; reused: att@v out, then P
constexpr size_t OFF_LV   = OFF_Q    + (size_t)65536*512*2;      // bf16 lv; Wraw overlays after langout
constexpr size_t OFF_SIMB = OFF_LV   + (size_t)65536*768*2;      // bf16 sim (B,H,4096,32)

// ---------------- prep: f32->bf16 converts + small language convs + zero atomics region ----
__global__ __launch_bounds__(256) void prep_kernel(
    const float* __restrict__ x,
    const float* __restrict__ w_vis, const float* __restrict__ w_q,
    const float* __restrict__ w_lv, const float* __restrict__ w_W,
    const float* __restrict__ w_mm,
    unsigned short* __restrict__ xb, unsigned short* __restrict__ wb,
    const float* __restrict__ l,
    const float* __restrict__ w_langp, const float* __restrict__ b_langp,
    const float* __restrict__ w_k, const float* __restrict__ b_k,
    const float* __restrict__ w_v, const float* __restrict__ b_v,
    const float* __restrict__ lmask,
    float* __restrict__ lang, float* __restrict__ kbuf, float* __restrict__ vbuf,
    float* __restrict__ zbase)
{
  const int bid = blockIdx.x, t = threadIdx.x;
  if (bid < 17088) {
    int i = bid * 256 + t;
    if (i >= 4374528) return;
    const float* src;
    unsigned short* dst;
    if (i < 4194304) { src = x + (size_t)i * 8; dst = xb + (size_t)i * 8; }
    else {
      int j = i - 4194304;
      dst = wb + (size_t)j * 8;
      if (j < 32768)       src = w_vis + (size_t)j * 8;
      else if (j < 65536)  src = w_q  + (size_t)(j - 32768) * 8;
      else if (j < 114688) src = w_lv + (size_t)(j - 65536) * 8;
      else if (j < 147456) src = w_W  + (size_t)(j - 114688) * 8;
      else                 src = w_mm + (size_t)(j - 147456) * 8;
    }
    const f32x4* s = (const f32x4*)src;
    f32x4 a = s[0], b2 = s[1];
    ushort8 o;
#pragma unroll
    for (int j = 0; j < 4; ++j) { o[j] = f2bf(a[j]); o[j + 4] = f2bf(b2[j]); }
    *(ushort8*)dst = o;
  } else if (bid < 20672) {
    int sb = bid - 17088;
    int b = sb & 15, og = sb >> 4;          // og 0..223
    int ol = t >> 5, n = t & 31;
    const float* lb = l + (size_t)b * 768 * 32 + n;
    const float* wr;
    float bv;
    float* out;
    bool gel;
    if (og < 96) {
      int o = og * 8 + ol;
      wr = w_langp + (size_t)o * 768; bv = b_langp[o];
      out = &lang[((size_t)b * 768 + o) * 32 + n]; gel = true;
    } else if (og < 160) {
      int o = (og - 96) * 8 + ol;
      wr = w_k + (size_t)o * 768; bv = b_k[o];
      out = &kbuf[((size_t)b * 512 + o) * 32 + n]; gel = false;
    } else {
      int o = (og - 160) * 8 + ol;
      wr = w_v + (size_t)o * 768; bv = b_v[o];
      out = &vbuf[((size_t)b * 512 + o) * 32 + n]; gel = false;
    }
    float s = 0.f;
#pragma unroll 4
    for (int i = 0; i < 768; ++i) s += wr[i] * lb[(size_t)i * 32];
    s += bv;
    s = gel ? gelu_f(s) : s * lmask[b * 32 + n];
    *out = s;
  } else {
    size_t i = (size_t)(bid - 20672) * 256 + t;
    const f32x4 z = {0.f, 0.f, 0.f, 0.f};
    ((f32x4*)zbase)[i] = z;
  }
}

// ---------------- big GEMM, 2-phase dbuf: Y[m,n] = sum_k A[m,k]*Wb[n,k] + b[n] ----------------
template<bool GELU, bool STATS, bool OUTF32>
__global__ __launch_bounds__(256) void gemm_bt(
    const unsigned short* __restrict__ A, const unsigned short* __restrict__ Wb,
    const float* __restrict__ bias, void* __restrict__ Yout,
    float* __restrict__ statsraw, int N, int Kd, int nbn)
{
  __shared__ __align__(16) unsigned short As[2][128 * 64];
  __shared__ __align__(16) unsigned short Bs[2][128 * 64];
  const int t = threadIdx.x;
  const int wave = t >> 6, lane = t & 63;
  const int ln = lane & 15, quad = lane >> 4;
  const int wgid = xcd_swizzle(blockIdx.x, gridDim.x);
  const int mt = wgid / nbn, nt = wgid - mt * nbn;
  const int m0 = mt * 128, n0 = nt * 128;
  const int wm = (wave >> 1) * 64, wn = (wave & 1) * 64;
  const f32x4 fzero = {0.f, 0.f, 0.f, 0.f};
  f32x4 acc[4][4];
#pragma unroll
  for (int i = 0; i < 4; ++i)
#pragma unroll
    for (int j = 0; j < 4; ++j) acc[i][j] = fzero;
  const int lrow = lane >> 3;
  const int lch  = lane & 7;
  const unsigned short* Arow = A  + (size_t)(m0 + wave * 32 + lrow) * Kd + lch * 8;
  const unsigned short* Brow = Wb + (size_t)(n0 + wave * 32 + lrow) * Kd + lch * 8;

#define STAGE_BT(buf, k0)                                                     \
  {                                                                           \
    _Pragma("unroll")                                                         \
    for (int it = 0; it < 4; ++it) {                                          \
      int g = wave * 4 + it;                                                  \
      gload16(Arow + (size_t)(it * 8) * Kd + (k0), &As[buf][g * 512]);        \
      gload16(Brow + (size_t)(it * 8) * Kd + (k0), &Bs[buf][g * 512]);        \
    }                                                                         \
  }

  const int NT = Kd >> 6;
  STAGE_BT(0, 0)
  __syncthreads();
  int cur = 0;
  for (int kt = 0; kt < NT; ++kt) {
    if (kt + 1 < NT) STAGE_BT(cur ^ 1, (kt + 1) * 64)
#pragma unroll
    for (int kk = 0; kk < 64; kk += 32) {
      int c = (kk >> 3) + quad;
      bf16x8 af[4], bfr[4];
#pragma unroll
      for (int i = 0; i < 4; ++i)
        af[i] = *(const bf16x8*)&As[cur][(wm + i * 16 + ln) * 64 + c * 8];
#pragma unroll
      for (int j = 0; j < 4; ++j)
        bfr[j] = *(const bf16x8*)&Bs[cur][(wn + j * 16 + ln) * 64 + c * 8];
#pragma unroll
      for (int i = 0; i < 4; ++i)
#pragma unroll
        for (int j = 0; j < 4; ++j)
          acc[i][j] = __builtin_amdgcn_mfma_f32_16x16x32_bf16(af[i], bfr[j], acc[i][j], 0, 0, 0);
    }
    __syncthreads();   // drains next-tile staging (overlapped by the MFMAs above)
    cur ^= 1;
  }
  float bb[4];
#pragma unroll
  for (int j = 0; j < 4; ++j) bb[j] = bias[n0 + wn + j * 16 + ln];
#pragma unroll
  for (int i = 0; i < 4; ++i)
#pragma unroll
    for (int j = 0; j < 4; ++j)
#pragma unroll
      for (int r = 0; r < 4; ++r) {
        float v = acc[i][j][r] + bb[j];
        if (GELU) v = gelu_f(v);
        acc[i][j][r] = v;
        size_t row = (size_t)(m0 + wm + i * 16 + quad * 4 + r);
        size_t idx = row * N + (n0 + wn + j * 16 + ln);
        if (OUTF32) ((float*)Yout)[idx] = v;
        else ((unsigned short*)Yout)[idx] = f2bf(v);
      }
  if (STATS) {
    float* cs = (float*)As;
    cs[t] = 0.f;
    __syncthreads();
#pragma unroll
    for (int j = 0; j < 4; ++j) {
      float s = 0.f, s2 = 0.f;
#pragma unroll
      for (int i = 0; i < 4; ++i)
#pragma unroll
        for (int r = 0; r < 4; ++r) { float v = acc[i][j][r]; s += v; s2 += v * v; }
      s  += __shfl_xor(s, 16);  s  += __shfl_xor(s, 32);
      s2 += __shfl_xor(s2, 16); s2 += __shfl_xor(s2, 32);
      if (quad == 0) {
        int cl = wn + j * 16 + ln;
        atomicAdd(&cs[cl], s);
        atomicAdd(&cs[128 + cl], s2);
      }
    }
    __syncthreads();
    int bIdx = m0 >> 12;
    if (t < 128) atomicAdd(&statsraw[((size_t)bIdx * N + n0 + t) * 2], cs[t]);
    else atomicAdd(&statsraw[((size_t)bIdx * N + n0 + (t - 128)) * 2 + 1], cs[t]);
  }
}

// ---------------- fused vis|q|lv GEMM (2-phase dbuf): Ncat=1792, A read once --------------
__global__ __launch_bounds__(256) void gemm_fused3(
    const unsigned short* __restrict__ A, const unsigned short* __restrict__ Wcat,
    const float* __restrict__ b_vis, const float* __restrict__ b_q, const float* __restrict__ b_lv,
    unsigned short* __restrict__ visb, unsigned short* __restrict__ qout,
    unsigned short* __restrict__ lvout, float* __restrict__ srq, float* __restrict__ srlv)
{
  constexpr int NBN = 14, Kd = 512;
  __shared__ __align__(16) unsigned short As[2][128 * 64];
  __shared__ __align__(16) unsigned short Bs[2][128 * 64];
  const int t = threadIdx.x;
  const int wave = t >> 6, lane = t & 63;
  const int ln = lane & 15, quad = lane >> 4;
  const int wgid = xcd_swizzle(blockIdx.x, gridDim.x);
  const int mt = wgid / NBN, nt = wgid - mt * NBN;
  const int m0 = mt * 128, n0 = nt * 128;
  const int wm = (wave >> 1) * 64, wn = (wave & 1) * 64;
  const f32x4 fzero = {0.f, 0.f, 0.f, 0.f};
  f32x4 acc[4][4];
#pragma unroll
  for (int i = 0; i < 4; ++i)
#pragma unroll
    for (int j = 0; j < 4; ++j) acc[i][j] = fzero;
  const int lrow = lane >> 3;
  const int lch  = lane & 7;
  const unsigned short* Arow = A    + (size_t)(m0 + wave * 32 + lrow) * Kd + lch * 8;
  const unsigned short* Brow = Wcat + (size_t)(n0 + wave * 32 + lrow) * Kd + lch * 8;

  constexpr int NT = Kd >> 6;
  STAGE_BT(0, 0)
  __syncthreads();
  int cur = 0;
  for (int kt = 0; kt < NT; ++kt) {
    if (kt + 1 < NT) STAGE_BT(cur ^ 1, (kt + 1) * 64)
#pragma unroll
    for (int kk = 0; kk < 64; kk += 32) {
      int c = (kk >> 3) + quad;
      bf16x8 af[4], bfr[4];
#pragma unroll
      for (int i = 0; i < 4; ++i)
        af[i] = *(const bf16x8*)&As[cur][(wm + i * 16 + ln) * 64 + c * 8];
#pragma unroll
      for (int j = 0; j < 4; ++j)
        bfr[j] = *(const bf16x8*)&Bs[cur][(wn + j * 16 + ln) * 64 + c * 8];
#pragma unroll
      for (int i = 0; i < 4; ++i)
#pragma unroll
        for (int j = 0; j < 4; ++j)
          acc[i][j] = __builtin_amdgcn_mfma_f32_16x16x32_bf16(af[i], bfr[j], acc[i][j], 0, 0, 0);
    }
    __syncthreads();
    cur ^= 1;
  }
  int seg = (nt < 4) ? 0 : (nt < 8 ? 1 : 2);
  const float* bias = (seg == 0) ? b_vis : (seg == 1 ? b_q : b_lv);
  unsigned short* Y = (seg == 0) ? visb : (seg == 1 ? qout : lvout);
  float* statsraw   = (seg == 1) ? srq : srlv;
  const int nbase   = n0 - ((seg == 0) ? 0 : (seg == 1 ? 512 : 1024));
  const int Nseg    = (seg == 2) ? 768 : 512;

  float bb[4];
#pragma unroll
  for (int j = 0; j < 4; ++j) bb[j] = bias[nbase + wn + j * 16 + ln];
#pragma unroll
  for (int i = 0; i < 4; ++i)
#pragma unroll
    for (int j = 0; j < 4; ++j)
#pragma unroll
      for (int r = 0; r < 4; ++r) {
        float v = acc[i][j][r] + bb[j];
        if (seg == 0) v = gelu_f(v);
        acc[i][j][r] = v;
        size_t row = (size_t)(m0 + wm + i * 16 + quad * 4 + r);
        Y[row * Nseg + (nbase + wn + j * 16 + ln)] = f2bf(v);
      }
  if (seg != 0) {
    float* cs = (float*)As;
    cs[t] = 0.f;
    __syncthreads();
#pragma unroll
    for (int j = 0; j < 4; ++j) {
      float s = 0.f, s2 = 0.f;
#pragma unroll
      for (int i = 0; i < 4; ++i)
#pragma unroll
        for (int r = 0; r < 4; ++r) { float v = acc[i][j][r]; s += v; s2 += v * v; }
      s  += __shfl_xor(s, 16);  s  += __shfl_xor(s, 32);
      s2 += __shfl_xor(s2, 16); s2 += __shfl_xor(s2, 32);
      if (quad == 0) {
        int cl = wn + j * 16 + ln;
        atomicAdd(&cs[cl], s);
        atomicAdd(&cs[128 + cl], s2);
      }
    }
    __syncthreads();
    int bIdx = m0 >> 12;
    if (t < 128) atomicAdd(&statsraw[((size_t)bIdx * Nseg + nbase + t) * 2], cs[t]);
    else atomicAdd(&statsraw[((size_t)bIdx * Nseg + nbase + (t - 128)) * 2 + 1], cs[t]);
  }
}

// ---------------- fused sim + att-softmax + att@v + latt partial stats (MFMA) ----------------
__global__ __launch_bounds__(256) void simattv_kernel(
    const unsigned short* __restrict__ qraw, const float* __restrict__ srq,
    const float* __restrict__ kbuf, const float* __restrict__ vbuf,
    const float* __restrict__ lmask,
    unsigned short* __restrict__ simb, unsigned short* __restrict__ outb,
    float* __restrict__ pmx, float* __restrict__ psm)
{
  __shared__ __align__(16) unsigned short kThi[32][72];
  __shared__ __align__(16) unsigned short kTlo[32][72];
  __shared__ __align__(16) unsigned short vshi[64][40];
  __shared__ __align__(16) unsigned short vslo[64][40];
  __shared__ __align__(16) unsigned short pq[4][32][40];
  __shared__ float sm[64], srs[64], cb[32];
  __shared__ float wmax[4][32], wsum[4][32];

  const int qc = blockIdx.x, q0 = qc * 128, h = blockIdx.y, b = blockIdx.z;
  const int bh = b * 8 + h;
  const int t = threadIdx.x;
  const int wv = t >> 6, lane = t & 63, ln = lane & 15, quad = lane >> 4;
  const float scale = 0.04419417382415922f;  // 512^-0.5

  if (t < 64) {
    float s  = srq[(b * 512 + h * 64 + t) * 2];
    float s2 = srq[(b * 512 + h * 64 + t) * 2 + 1];
    float mean = s * (1.f / 4096.f);
    float var  = fmaxf(s2 * (1.f / 4096.f) - mean * mean, 0.f);
    sm[t]  = mean;
    srs[t] = rsqrtf(var + 1e-5f) * scale;
  }
  __syncthreads();

  const float* kb = kbuf + ((size_t)b * 512 + h * 64) * 32;
  const float* vb = vbuf + ((size_t)b * 512 + h * 64) * 32;
  for (int e = t; e < 2048; e += 256) {
    int d = e >> 5, n = e & 31;
    float kv = kb[e] * srs[d];
    unsigned short khi = f2bf(kv);
    kThi[n][d] = khi;
    kTlo[n][d] = f2bf(kv - bf2f(khi));
    float vv = vb[e];
    unsigned short vhi = f2bf(vv);
    vshi[d][n] = vhi;
    vslo[d][n] = f2bf(vv - bf2f(vhi));
  }
  if (t < 32) {
    float s = 0.f;
#pragma unroll 8
    for (int d = 0; d < 64; ++d) s += sm[d] * srs[d] * kb[d * 32 + t];
    cb[t] = 10000.f * (lmask[b * 32 + t] - 1.f) - s;
  }

  const unsigned short* qbase = qraw + ((size_t)(b * 4096) + q0 + wv * 32) * 512 + h * 64;
  bf16x8 qfr[2][2];
#pragma unroll
  for (int qf = 0; qf < 2; ++qf)
#pragma unroll
    for (int kf = 0; kf < 2; ++kf)
      qfr[qf][kf] = *(const bf16x8*)(qbase + (size_t)(qf * 16 + ln) * 512 + kf * 32 + quad * 8);
  __syncthreads();

  const f32x4 fz = {0.f, 0.f, 0.f, 0.f};
  f32x4 accS[2][2] = {{fz, fz}, {fz, fz}};
#pragma unroll
  for (int kf = 0; kf < 2; ++kf) {
#pragma unroll
    for (int nf = 0; nf < 2; ++nf) {
      bf16x8 kh = *(const bf16x8*)&kThi[nf * 16 + ln][kf * 32 + quad * 8];
      bf16x8 kl = *(const bf16x8*)&kTlo[nf * 16 + ln][kf * 32 + quad * 8];
#pragma unroll
      for (int qf = 0; qf < 2; ++qf) {
        accS[qf][nf] = __builtin_amdgcn_mfma_f32_16x16x32_bf16(qfr[qf][kf], kh, accS[qf][nf], 0, 0, 0);
        accS[qf][nf] = __builtin_amdgcn_mfma_f32_16x16x32_bf16(qfr[qf][kf], kl, accS[qf][nf], 0, 0, 0);
      }
    }
  }
  float cb0 = cb[ln], cb1 = cb[16 + ln];
#pragma unroll
  for (int qf = 0; qf < 2; ++qf)
#pragma unroll
    for (int r = 0; r < 4; ++r) {
      accS[qf][0][r] += cb0;
      accS[qf][1][r] += cb1;
    }
  {
    unsigned short* sgb = simb + ((size_t)bh * 4096 + q0 + wv * 32) * 32;
#pragma unroll
    for (int qf = 0; qf < 2; ++qf)
#pragma unroll
      for (int r = 0; r < 4; ++r) {
        size_t rowo = (size_t)(qf * 16 + quad * 4 + r) * 32;
        sgb[rowo + ln]      = f2bf(accS[qf][0][r]);
        sgb[rowo + 16 + ln] = f2bf(accS[qf][1][r]);
      }
  }
#pragma unroll
  for (int nf = 0; nf < 2; ++nf) {
    float m = accS[0][nf][0];
#pragma unroll
    for (int r = 1; r < 4; ++r) m = fmaxf(m, accS[0][nf][r]);
#pragma unroll
    for (int r = 0; r < 4; ++r) m = fmaxf(m, accS[1][nf][r]);
    m = fmaxf(m, __shfl_xor(m, 16));
    m = fmaxf(m, __shfl_xor(m, 32));
    float s = 0.f;
#pragma unroll
    for (int qf = 0; qf < 2; ++qf)
#pragma unroll
      for (int r = 0; r < 4; ++r) s += __expf(accS[qf][nf][r] - m);
    s += __shfl_xor(s, 16);
    s += __shfl_xor(s, 32);
    if (quad == 0) { wmax[wv][nf * 16 + ln] = m; wsum[wv][nf * 16 + ln] = s; }
  }
#pragma unroll
  for (int qf = 0; qf < 2; ++qf) {
#pragma unroll
    for (int r = 0; r < 4; ++r) {
      float a0 = accS[qf][0][r], a1 = accS[qf][1][r];
      float m = fmaxf(a0, a1);
      m = fmaxf(m, __shfl_xor(m, 1));
      m = fmaxf(m, __shfl_xor(m, 2));
      m = fmaxf(m, __shfl_xor(m, 4));
      m = fmaxf(m, __shfl_xor(m, 8));
      float e0 = __expf(a0 - m), e1 = __expf(a1 - m);
      float s = e0 + e1;
      s += __shfl_xor(s, 1);
      s += __shfl_xor(s, 2);
      s += __shfl_xor(s, 4);
      s += __shfl_xor(s, 8);
      float inv = 1.f / s;
      int row = qf * 16 + quad * 4 + r;
      pq[wv][row][ln]      = f2bf(e0 * inv);
      pq[wv][row][16 + ln] = f2bf(e1 * inv);
    }
  }
  __syncthreads();
  bf16x8 vfh[4], vfl[4];
#pragma unroll
  for (int mf = 0; mf < 4; ++mf) {
    vfh[mf] = *(const bf16x8*)&vshi[mf * 16 + ln][quad * 8];
    vfl[mf] = *(const bf16x8*)&vslo[mf * 16 + ln][quad * 8];
  }
#pragma unroll
  for (int nf = 0; nf < 2; ++nf) {
    bf16x8 pb = *(const bf16x8*)&pq[wv][nf * 16 + ln][quad * 8];
    f32x4 accO[4] = {fz, fz, fz, fz};
#pragma unroll
    for (int mf = 0; mf < 4; ++mf) {
      accO[mf] = __builtin_amdgcn_mfma_f32_16x16x32_bf16(vfh[mf], pb, accO[mf], 0, 0, 0);
      accO[mf] = __builtin_amdgcn_mfma_f32_16x16x32_bf16(vfl[mf], pb, accO[mf], 0, 0, 0);
    }
    unsigned short* op = outb + ((size_t)(b * 4096) + q0 + wv * 32 + nf * 16 + ln) * 512 + h * 64;
#pragma unroll
    for (int mf = 0; mf < 4; ++mf) {
      us4 o;
#pragma unroll
      for (int r = 0; r < 4; ++r) o[r] = f2bf(accO[mf][r]);
      *(us4*)(op + mf * 16 + quad * 4) = o;
    }
  }
  __syncthreads();
  if (t < 32) {
    float M = wmax[0][t], S = wsum[0][t];
#pragma unroll
    for (int g = 1; g < 4; ++g) {
      float m2 = wmax[g][t], s2 = wsum[g][t];
      if (m2 > M) { S = S * __expf(M - m2) + s2; M = m2; }
      else S += s2 * __expf(m2 - M);
    }
    pmx[((size_t)qc * 128 + bh) * 32 + t] = M;
    psm[((size_t)qc * 128 + bh) * 32 + t] = S;
  }
}

// ---------------- lang_out[b,h,c,n] += sum_q latt[n,q]*lvnorm[c,q] ----------------
__global__ __launch_bounds__(256) void langout_acc_kernel(
    const unsigned short* __restrict__ simb, const float* __restrict__ pmx,
    const float* __restrict__ psm, const unsigned short* __restrict__ lvraw,
    const float* __restrict__ srlv, float* __restrict__ lacc)
{
  __shared__ __align__(16) float pt[64][32];
  __shared__ __align__(16) float lvt[64][96];
  __shared__ float cm[96], cr[96], lm[32], li[32];
  int bh = blockIdx.x, b = bh >> 3, h = bh & 7;
  int qs0 = blockIdx.y * 512;
  int t = threadIdx.x;
  if (t < 96) {
    float s  = srlv[(b * 768 + h * 96 + t) * 2];
    float s2 = srlv[(b * 768 + h * 96 + t) * 2 + 1];
    float mean = s * (1.f / 4096.f);
    float var  = fmaxf(s2 * (1.f / 4096.f) - mean * mean, 0.f);
    cm[t] = mean;
    cr[t] = rsqrtf(var + 1e-5f);
  } else if (t >= 128 && t < 160) {
    int n = t - 128;
    float M = -1e30f, S = 0.f;
#pragma unroll 4
    for (int c = 0; c < 32; ++c) {
      float m2 = pmx[((size_t)c * 128 + bh) * 32 + n];
      float s2 = psm[((size_t)c * 128 + bh) * 32 + n];
      if (m2 > M) { S = S * __expf(M - m2) + s2; M = m2; }
      else S += s2 * __expf(m2 - M);
    }
    lm[n] = M;
    li[n] = 1.f / S;
  }
  __syncthreads();
  int n = t & 31, cg = t >> 5;
  float acc[12];
#pragma unroll
  for (int r = 0; r < 12; ++r) acc[r] = 0.f;
  for (int c0 = 0; c0 < 512; c0 += 64) {
    if (c0) __syncthreads();
#pragma unroll
    for (int i = 0; i < 8; ++i) {
      int e = t + 256 * i;
      int ql = e >> 5, nn = e & 31;
      float x = bf2f(simb[((size_t)bh * 4096 + qs0 + c0 + ql) * 32 + nn]);
      pt[ql][nn] = __expf(x - lm[nn]) * li[nn];
    }
#pragma unroll
    for (int i = 0; i < 24; ++i) {
      int e = t + 256 * i;
      int ql = e / 96, cc = e % 96;
      float v = bf2f(lvraw[((size_t)(b * 4096) + qs0 + c0 + ql) * 768 + h * 96 + cc]);
      lvt[ql][cc] = (v - cm[cc]) * cr[cc];
    }
    __syncthreads();
    for (int q = 0; q < 64; ++q) {
      float pv = pt[q][n];
      const f32x4* lp = (const f32x4*)&lvt[q][cg * 12];
      f32x4 a0 = lp[0], a1 = lp[1], a2 = lp[2];
      acc[0] += pv * a0[0]; acc[1] += pv * a0[1]; acc[2]  += pv * a0[2]; acc[3]  += pv * a0[3];
      acc[4] += pv * a1[0]; acc[5] += pv * a1[1]; acc[6]  += pv * a1[2]; acc[7]  += pv * a1[3];
      acc[8] += pv * a2[0]; acc[9] += pv * a2[1]; acc[10] += pv * a2[2]; acc[11] += pv * a2[3];
    }
  }
#pragma unroll
  for (int r = 0; r < 12; ++r)
    atomicAdd(&lacc[((size_t)b * 768 + h * 96 + cg * 12 + r) * 32 + n], acc[r]);
}

// ---------------- P = vis * inorm(Wout), stats inline from srw ----------------
__global__ __launch_bounds__(256) void prod_kernel(
    const unsigned short* __restrict__ visb, const unsigned short* __restrict__ wraw,
    const float* __restrict__ srw, unsigned short* __restrict__ P)
{
  size_t idx = ((size_t)blockIdx.x * 256 + threadIdx.x) * 8;
  int b = (int)(idx >> 21);
  int c = (int)(idx & 511);
  ushort8 vv = *(const ushort8*)&visb[idx];
  ushort8 wv = *(const ushort8*)&wraw[idx];
  ushort8 pv;
#pragma unroll
  for (int i = 0; i < 8; ++i) {
    float s  = srw[(b * 512 + c + i) * 2];
    float s2 = srw[(b * 512 + c + i) * 2 + 1];
    float mean = s * (1.f / 4096.f);
    float var  = fmaxf(s2 * (1.f / 4096.f) - mean * mean, 0.f);
    float rs   = rsqrtf(var + 1e-5f);
    pv[i] = f2bf(bf2f(vv[i]) * ((bf2f(wv[i]) - mean) * rs));
  }
  *(ushort8*)&P[idx] = pv;
}

// ---------------- langW conv + inorm over NL + *lang fuse (writes p2 directly) ----------------
__global__ __launch_bounds__(256) void langW_kernel(
    const float* __restrict__ lacc, const float* __restrict__ w,
    const float* __restrict__ bias, const float* __restrict__ lmask,
    const float* __restrict__ lang, float* __restrict__ p2)
{
  int b = blockIdx.x, og = blockIdx.y;
  int ol = threadIdx.x >> 5, n = threadIdx.x & 31;
  int o = og * 8 + ol;
  const float* ab = lacc + (size_t)b * 768 * 32 + n;
  const float* wr = w + (size_t)o * 768;
  float s = 0.f;
#pragma unroll 4
  for (int i = 0; i < 768; ++i) s += wr[i] * ab[(size_t)i * 32];
  float y = s * lmask[b * 32 + n] + bias[o];
  float m = y;
#pragma unroll
  for (int off = 16; off >= 1; off >>= 1) m += __shfl_xor(m, off);
  m *= (1.f / 32.f);
  float d = y - m;
  float vv = d * d;
#pragma unroll
  for (int off = 16; off >= 1; off >>= 1) vv += __shfl_xor(vv, off);
  vv *= (1.f / 32.f);
  size_t idx = ((size_t)b * 768 + o) * 32 + n;
  p2[idx] = lang[idx] * (d * rsqrtf(vv + 1e-5f));
}

// ---------------- langmm conv + gelu, store transposed (B,NL,CL) f32 ----------------
__global__ __launch_bounds__(256) void langmm_kernel(
    const float* __restrict__ p2, const float* __restrict__ w,
    const float* __restrict__ bias, float* __restrict__ out1)
{
  int b = blockIdx.x, og = blockIdx.y;
  int ol = threadIdx.x >> 5, n = threadIdx.x & 31;
  int o = og * 8 + ol;
  const float* pb = p2 + (size_t)b * 768 * 32 + n;
  const float* wr = w + (size_t)o * 768;
  float s = 0.f;
#pragma unroll 4
  for (int i = 0; i < 768; ++i) s += wr[i] * pb[(size_t)i * 32];
  s = gelu_f(s + bias[o]);
  __shared__ float tile[8][32];
  tile[ol][n] = s;
  __syncthreads();
  int nn = threadIdx.x >> 3, cl = threadIdx.x & 7;
  out1[((size_t)b * 32 + nn) * 768 + og * 8 + cl] = tile[cl][nn];
}

// ---------------- launch ----------------
extern "C" void kernel_launch(void* const* d_in, const int* in_sizes, int n_in,
                              void* d_out, int out_size, void* d_ws, size_t ws_size,
                              hipStream_t stream)
{
  (void)in_sizes; (void)n_in; (void)out_size; (void)ws_size;
  const float* x       = (const float*)d_in[0];
  const float* l       = (const float*)d_in[1];
  const float* lmask   = (const float*)d_in[2];
  const float* w_vis   = (const float*)d_in[3];
  const float* b_vis   = (const float*)d_in[4];
  const float* w_langp = (const float*)d_in[5];
  const float* b_langp = (const float*)d_in[6];
  const float* w_q     = (const float*)d_in[7];
  const float* b_q     = (const float*)d_in[8];
  const float* w_k     = (const float*)d_in[9];
  const float* b_k     = (const float*)d_in[10];
  const float* w_v     = (const float*)d_in[11];
  const float* b_v     = (const float*)d_in[12];
  const float* w_lv    = (const float*)d_in[13];
  const float* b_lv    = (const float*)d_in[14];
  const float* w_W     = (const float*)d_in[15];
  const float* b_W     = (const float*)d_in[16];
  const float* w_langW = (const float*)d_in[17];
  const float* b_langW = (const float*)d_in[18];
  const float* w_mm    = (const float*)d_in[19];
  const float* b_mm    = (const float*)d_in[20];
  const float* w_langmm= (const float*)d_in[21];
  const float* b_langmm= (const float*)d_in[22];

  char* ws = (char*)d_ws;
  float* srq  = (float*)(ws + OFF_SRQ);
  float* srlv = (float*)(ws + OFF_SRLV);
  float* srw  = (float*)(ws + OFF_SRW);
  float* lacc = (float*)(ws + OFF_LACC);
  float* kbuf = (float*)(ws + OFF_KBUF);
  float* vbuf = (float*)(ws + OFF_VBUF);
  float* lang = (float*)(ws + OFF_LANG);
  float* p2   = (float*)(ws + OFF_P2);
  float* pmx  = (float*)(ws + OFF_PMX);
  float* psm  = (float*)(ws + OFF_PSM);
  unsigned short* wb    = (unsigned short*)(ws + OFF_WB);
  unsigned short* wbW   = wb + 917504;
  unsigned short* wbmm  = wb + 1179648;
  unsigned short* qraw  = (unsigned short*)(ws + OFF_Q);
  unsigned short* lvraw = (unsigned short*)(ws + OFF_LV);
  unsigned short* wraw  = (unsigned short*)(ws + OFF_LV);
  unsigned short* simb  = (unsigned short*)(ws + OFF_SIMB);
  float* out0 = (float*)d_out;
  float* out1 = out0 + (size_t)16 * 4096 * 512;
  unsigned short* visb = (unsigned short*)d_out;                 // [0,64MB)
  unsigned short* xb   = (unsigned short*)d_out + 33554432;      // [64,128MB)

  // prep: converts + small convs + zero of atomic accumulators
  prep_kernel<<<21112, 256, 0, stream>>>(x, w_vis, w_q, w_lv, w_W, w_mm, xb, wb,
                                         l, w_langp, b_langp, w_k, b_k, w_v, b_v,
                                         lmask, lang, kbuf, vbuf, (float*)ws);

  // fused vis|q|lv GEMM: A (xb) read once, n-fastest + XCD swizzle, 2-phase dbuf
  gemm_fused3<<<512 * 14, 256, 0, stream>>>(xb, wb, b_vis, b_q, b_lv,
                                            visb, qraw, lvraw, srq, srlv);

  // attention (fused sim+softmax+PV+latt partials, MFMA; q-norm stats inline)
  simattv_kernel<<<dim3(32, 8, 16), 256, 0, stream>>>(qraw, srq, kbuf, vbuf, lmask, simb, qraw, pmx, psm);
  langout_acc_kernel<<<dim3(128, 8), 256, 0, stream>>>(simb, pmx, psm, lvraw, srlv, lacc);

  // visual output path
  gemm_bt<false, true,  false><<<512 * 4, 256, 0, stream>>>(qraw, wbW, b_W, wraw, srw, 512, 512, 4);
  prod_kernel<<<16384, 256, 0, stream>>>(visb, wraw, srw, qraw);
  gemm_bt<true,  false, true ><<<512 * 4, 256, 0, stream>>>(qraw, wbmm, b_mm, out0, nullptr, 512, 512, 4);

  // language output path
  langW_kernel<<<dim3(16, 96), 256, 0, stream>>>(lacc, w_langW, b_langW, lmask, lang, p2);
  langmm_kernel<<<dim3(16, 96), 256, 0, stream>>>(p2, w_langmm, b_langmm, out1);
}

// Round 6
// 1164.569 us; speedup vs baseline: 1.1327x; 1.0438x over previous
//
#include <hip/hip_runtime.h>
#include <cstdint>
#include <cstddef>

// B=16, HW=4096, D=512, CL=768, K=512, V=512, NL=32, H=8.
// I/O FLOAT32. Internal big buffers bf16. ws ~214 MB.
// d_out hosting: [0,64MB)=visb bf16, [64,128MB)=xb bf16; both dead before mm GEMM writes f32.
// GEMMs: 256x256 tile, 8 waves, BK=64, double-buffered LDS (128KB), prefetch-before-compute,
// ONE __syncthreads per K-step, XOR-swizzled LDS (pre-swizzled gload source + swizzled ds_read).
// global_load_lds dest is WAVE-UNIFORM base (+ lane*16B implicit) per m104/m108 semantics.

typedef __bf16 bf16x8 __attribute__((ext_vector_type(8)));
typedef float f32x4 __attribute__((ext_vector_type(4)));
typedef unsigned short ushort8 __attribute__((ext_vector_type(8)));
typedef unsigned short us4 __attribute__((ext_vector_type(4)));

__device__ __forceinline__ float bf2f(unsigned short u) {
  union { unsigned int i; float f; } c; c.i = ((unsigned int)u) << 16; return c.f;
}
__device__ __forceinline__ unsigned short f2bf(float f) {
  union { float f; unsigned int i; } c; c.f = f;
  unsigned int r = c.i + 0x7FFFu + ((c.i >> 16) & 1u);
  return (unsigned short)(r >> 16);
}
__device__ __forceinline__ float gelu_f(float x) {
  return 0.5f * x * (1.f + erff(x * 0.70710678118654752f));
}
__device__ __forceinline__ void gload16(const void* g, void* l) {
  __builtin_amdgcn_global_load_lds(
      (__attribute__((address_space(1))) unsigned int*)g,
      (__attribute__((address_space(3))) unsigned int*)l, 16, 0, 0);
}
// bijective XCD swizzle (m204): contiguous wgid chunk per XCD
__device__ __forceinline__ int xcd_swizzle(int orig, int nwg) {
  int qd = nwg >> 3, r = nwg & 7;
  int xcd = orig & 7, idx = orig >> 3;
  return (xcd < r ? xcd * (qd + 1) : r * (qd + 1) + (xcd - r) * qd) + idx;
}

// ---------------- workspace layout (bytes) ----------------
constexpr size_t OFF_SRQ  = 0;                                   // f32 [16][512][2] raw sum/sumsq
constexpr size_t OFF_SRLV = OFF_SRQ  + (size_t)16*512*2*4;       // f32 [16][768][2]
constexpr size_t OFF_SRW  = OFF_SRLV + (size_t)16*768*2*4;       // f32 [16][512][2]
constexpr size_t OFF_LACC = OFF_SRW  + (size_t)16*512*2*4;       // f32 [16][768][32]
constexpr size_t SZ_ZERO  = OFF_LACC + (size_t)16*768*32*4;      // zero [0, SZ_ZERO) each launch
constexpr size_t OFF_KBUF = SZ_ZERO;                             // f32 [16][512][32]
constexpr size_t OFF_VBUF = OFF_KBUF + (size_t)16*512*32*4;
constexpr size_t OFF_LANG = OFF_VBUF + (size_t)16*512*32*4;      // f32 [16][768][32]
constexpr size_t OFF_P2   = OFF_LANG + (size_t)16*768*32*4;      // f32 [16][768][32]
constexpr size_t OFF_PMX  = OFF_P2   + (size_t)16*768*32*4;      // f32 [32][128][32]
constexpr size_t OFF_PSM  = OFF_PMX  + (size_t)32*128*32*4;      // f32 [32][128][32]
constexpr size_t OFF_WB   = OFF_PSM  + (size_t)32*128*32*4;      // bf16 weights: vis|q|lv (cat [1792][512]), W, mm
constexpr size_t OFF_Q    = OFF_WB   + (size_t)1441792*2;        // bf16 q; reused: att@v out, then P
constexpr size_t OFF_LV   = OFF_Q    + (size_t)65536*512*2;      // bf16 lv; Wraw overlays after langout
constexpr size_t OFF_SIMB = OFF_LV   + (size_t)65536*768*2;      // bf16 sim (B,H,4096,32)

// ---------------- prep: f32->bf16 converts + small language convs + zero atomics region ----
__global__ __launch_bounds__(256) void prep_kernel(
    const float* __restrict__ x,
    const float* __restrict__ w_vis, const float* __restrict__ w_q,
    const float* __restrict__ w_lv, const float* __restrict__ w_W,
    const float* __restrict__ w_mm,
    unsigned short* __restrict__ xb, unsigned short* __restrict__ wb,
    const float* __restrict__ l,
    const float* __restrict__ w_langp, const float* __restrict__ b_langp,
    const float* __restrict__ w_k, const float* __restrict__ b_k,
    const float* __restrict__ w_v, const float* __restrict__ b_v,
    const float* __restrict__ lmask,
    float* __restrict__ lang, float* __restrict__ kbuf, float* __restrict__ vbuf,
    float* __restrict__ zbase)
{
  const int bid = blockIdx.x, t = threadIdx.x;
  if (bid < 17088) {
    int i = bid * 256 + t;
    if (i >= 4374528) return;
    const float* src;
    unsigned short* dst;
    if (i < 4194304) { src = x + (size_t)i * 8; dst = xb + (size_t)i * 8; }
    else {
      int j = i - 4194304;
      dst = wb + (size_t)j * 8;
      if (j < 32768)       src = w_vis + (size_t)j * 8;
      else if (j < 65536)  src = w_q  + (size_t)(j - 32768) * 8;
      else if (j < 114688) src = w_lv + (size_t)(j - 65536) * 8;
      else if (j < 147456) src = w_W  + (size_t)(j - 114688) * 8;
      else                 src = w_mm + (size_t)(j - 147456) * 8;
    }
    const f32x4* s = (const f32x4*)src;
    f32x4 a = s[0], b2 = s[1];
    ushort8 o;
#pragma unroll
    for (int j = 0; j < 4; ++j) { o[j] = f2bf(a[j]); o[j + 4] = f2bf(b2[j]); }
    *(ushort8*)dst = o;
  } else if (bid < 20672) {
    int sb = bid - 17088;
    int b = sb & 15, og = sb >> 4;          // og 0..223
    int ol = t >> 5, n = t & 31;
    const float* lb = l + (size_t)b * 768 * 32 + n;
    const float* wr;
    float bv;
    float* out;
    bool gel;
    if (og < 96) {
      int o = og * 8 + ol;
      wr = w_langp + (size_t)o * 768; bv = b_langp[o];
      out = &lang[((size_t)b * 768 + o) * 32 + n]; gel = true;
    } else if (og < 160) {
      int o = (og - 96) * 8 + ol;
      wr = w_k + (size_t)o * 768; bv = b_k[o];
      out = &kbuf[((size_t)b * 512 + o) * 32 + n]; gel = false;
    } else {
      int o = (og - 160) * 8 + ol;
      wr = w_v + (size_t)o * 768; bv = b_v[o];
      out = &vbuf[((size_t)b * 512 + o) * 32 + n]; gel = false;
    }
    float s = 0.f;
#pragma unroll 4
    for (int i = 0; i < 768; ++i) s += wr[i] * lb[(size_t)i * 32];
    s += bv;
    s = gel ? gelu_f(s) : s * lmask[b * 32 + n];
    *out = s;
  } else {
    size_t i = (size_t)(bid - 20672) * 256 + t;
    const f32x4 z = {0.f, 0.f, 0.f, 0.f};
    ((f32x4*)zbase)[i] = z;
  }
}

// ---- 256x256 GEMM staging (shared by gemm_bt and gemm_fused3) ----
// Wave w, lane l: LDS dest base (wave-uniform) = r*4096 + w*512 shorts; lane l lands at +l*8 shorts.
// That LDS slot is row (r*64 + w*8 + (l>>3)), chunk (l&7). Global source for that lane is row
// (m0 + r*64 + srow8) with chunk ((l&7) ^ (srow8&7)) where srow8 = w*8 + (l>>3)  (XOR involution).
// Read side: row R, logical chunk c -> LDS chunk (c ^ (R&7)).
#define STG256(buf, k0)                                                            \
  {                                                                                \
    _Pragma("unroll")                                                              \
    for (int r = 0; r < 4; ++r) {                                                  \
      gload16(Asrc + (size_t)(r * 64) * Kd + (k0), &As[buf][r * 4096 + wave * 512]); \
      gload16(Bsrc + (size_t)(r * 64) * Kd + (k0), &Bs[buf][r * 4096 + wave * 512]); \
    }                                                                              \
  }

// ---------------- big GEMM, 256^2 2-phase dbuf: Y[m,n] = sum_k A[m,k]*Wb[n,k] + b[n] --------
template<bool GELU, bool STATS, bool OUTF32>
__global__ __launch_bounds__(512, 2) void gemm_bt(
    const unsigned short* __restrict__ A, const unsigned short* __restrict__ Wb,
    const float* __restrict__ bias, void* __restrict__ Yout,
    float* __restrict__ statsraw, int N, int Kd, int nbn)
{
  __shared__ __align__(16) unsigned short As[2][256 * 64];
  __shared__ __align__(16) unsigned short Bs[2][256 * 64];
  const int t = threadIdx.x;
  const int wave = t >> 6, lane = t & 63;
  const int ln = lane & 15, quad = lane >> 4;
  const int wgid = xcd_swizzle(blockIdx.x, gridDim.x);
  const int mt = wgid / nbn, nt = wgid - mt * nbn;
  const int m0 = mt * 256, n0 = nt * 256;
  const int wm = (wave >> 2) * 128;   // 0 / 128
  const int wn = (wave & 3) * 64;     // 0..192
  const f32x4 fzero = {0.f, 0.f, 0.f, 0.f};
  f32x4 acc[8][4];
#pragma unroll
  for (int i = 0; i < 8; ++i)
#pragma unroll
    for (int j = 0; j < 4; ++j) acc[i][j] = fzero;
  const int srow8 = wave * 8 + (lane >> 3);            // 0..63
  const int sch2  = (lane & 7) ^ (srow8 & 7);          // involutive source swizzle
  const unsigned short* Asrc = A  + (size_t)(m0 + srow8) * Kd + sch2 * 8;
  const unsigned short* Bsrc = Wb + (size_t)(n0 + srow8) * Kd + sch2 * 8;

  const int NT = Kd >> 6;
  STG256(0, 0)
  __syncthreads();
  int cur = 0;
  for (int kt = 0; kt < NT; ++kt) {
    if (kt + 1 < NT) STG256(cur ^ 1, (kt + 1) * 64)
#pragma unroll
    for (int kk = 0; kk < 2; ++kk) {
      const int c = kk * 4 + quad;
      bf16x8 af[8], bfr[4];
#pragma unroll
      for (int i = 0; i < 8; ++i) {
        int R = wm + i * 16 + ln;
        af[i] = *(const bf16x8*)&As[cur][R * 64 + ((c ^ (R & 7)) & 7) * 8];
      }
#pragma unroll
      for (int j = 0; j < 4; ++j) {
        int R = wn + j * 16 + ln;
        bfr[j] = *(const bf16x8*)&Bs[cur][R * 64 + ((c ^ (R & 7)) & 7) * 8];
      }
#pragma unroll
      for (int i = 0; i < 8; ++i)
#pragma unroll
        for (int j = 0; j < 4; ++j)
          acc[i][j] = __builtin_amdgcn_mfma_f32_16x16x32_bf16(af[i], bfr[j], acc[i][j], 0, 0, 0);
    }
    __syncthreads();   // next-tile staging drained here (overlapped by MFMAs above)
    cur ^= 1;
  }
  float bb[4];
#pragma unroll
  for (int j = 0; j < 4; ++j) bb[j] = bias[n0 + wn + j * 16 + ln];
#pragma unroll
  for (int i = 0; i < 8; ++i)
#pragma unroll
    for (int j = 0; j < 4; ++j)
#pragma unroll
      for (int r = 0; r < 4; ++r) {
        float v = acc[i][j][r] + bb[j];
        if (GELU) v = gelu_f(v);
        acc[i][j][r] = v;
        size_t row = (size_t)(m0 + wm + i * 16 + quad * 4 + r);
        size_t idx = row * N + (n0 + wn + j * 16 + ln);
        if (OUTF32) ((float*)Yout)[idx] = v;
        else ((unsigned short*)Yout)[idx] = f2bf(v);
      }
  if (STATS) {
    float* cs = (float*)As;   // 512 floats: [0..255]=sum, [256..511]=sumsq
    cs[t] = 0.f;
    __syncthreads();
#pragma unroll
    for (int j = 0; j < 4; ++j) {
      float s = 0.f, s2 = 0.f;
#pragma unroll
      for (int i = 0; i < 8; ++i)
#pragma unroll
        for (int r = 0; r < 4; ++r) { float v = acc[i][j][r]; s += v; s2 += v * v; }
      s  += __shfl_xor(s, 16);  s  += __shfl_xor(s, 32);
      s2 += __shfl_xor(s2, 16); s2 += __shfl_xor(s2, 32);
      if (quad == 0) {
        int cl = wn + j * 16 + ln;
        atomicAdd(&cs[cl], s);
        atomicAdd(&cs[256 + cl], s2);
      }
    }
    __syncthreads();
    int bIdx = m0 >> 12;
    int col = t & 255;
    if (t < 256) atomicAdd(&statsraw[((size_t)bIdx * N + n0 + col) * 2], cs[col]);
    else atomicAdd(&statsraw[((size_t)bIdx * N + n0 + col) * 2 + 1], cs[256 + col]);
  }
}

// ---------------- fused vis|q|lv GEMM (256^2 2-phase dbuf): Ncat=1792, A read once ---------
// nt 0-1: gelu->visb ; 2-3: stats->qout ; 4-6: stats->lvout. 256 | segment boundaries.
__global__ __launch_bounds__(512, 2) void gemm_fused3(
    const unsigned short* __restrict__ A, const unsigned short* __restrict__ Wcat,
    const float* __restrict__ b_vis, const float* __restrict__ b_q, const float* __restrict__ b_lv,
    unsigned short* __restrict__ visb, unsigned short* __restrict__ qout,
    unsigned short* __restrict__ lvout, float* __restrict__ srq, float* __restrict__ srlv)
{
  constexpr int NBN = 7, Kd = 512;
  __shared__ __align__(16) unsigned short As[2][256 * 64];
  __shared__ __align__(16) unsigned short Bs[2][256 * 64];
  const int t = threadIdx.x;
  const int wave = t >> 6, lane = t & 63;
  const int ln = lane & 15, quad = lane >> 4;
  const int wgid = xcd_swizzle(blockIdx.x, gridDim.x);
  const int mt = wgid / NBN, nt = wgid - mt * NBN;
  const int m0 = mt * 256, n0 = nt * 256;
  const int wm = (wave >> 2) * 128;
  const int wn = (wave & 3) * 64;
  const f32x4 fzero = {0.f, 0.f, 0.f, 0.f};
  f32x4 acc[8][4];
#pragma unroll
  for (int i = 0; i < 8; ++i)
#pragma unroll
    for (int j = 0; j < 4; ++j) acc[i][j] = fzero;
  const int srow8 = wave * 8 + (lane >> 3);
  const int sch2  = (lane & 7) ^ (srow8 & 7);
  const unsigned short* Asrc = A    + (size_t)(m0 + srow8) * Kd + sch2 * 8;
  const unsigned short* Bsrc = Wcat + (size_t)(n0 + srow8) * Kd + sch2 * 8;

  constexpr int NT = Kd >> 6;
  STG256(0, 0)
  __syncthreads();
  int cur = 0;
  for (int kt = 0; kt < NT; ++kt) {
    if (kt + 1 < NT) STG256(cur ^ 1, (kt + 1) * 64)
#pragma unroll
    for (int kk = 0; kk < 2; ++kk) {
      const int c = kk * 4 + quad;
      bf16x8 af[8], bfr[4];
#pragma unroll
      for (int i = 0; i < 8; ++i) {
        int R = wm + i * 16 + ln;
        af[i] = *(const bf16x8*)&As[cur][R * 64 + ((c ^ (R & 7)) & 7) * 8];
      }
#pragma unroll
      for (int j = 0; j < 4; ++j) {
        int R = wn + j * 16 + ln;
        bfr[j] = *(const bf16x8*)&Bs[cur][R * 64 + ((c ^ (R & 7)) & 7) * 8];
      }
#pragma unroll
      for (int i = 0; i < 8; ++i)
#pragma unroll
        for (int j = 0; j < 4; ++j)
          acc[i][j] = __builtin_amdgcn_mfma_f32_16x16x32_bf16(af[i], bfr[j], acc[i][j], 0, 0, 0);
    }
    __syncthreads();
    cur ^= 1;
  }
  const int seg = (nt < 2) ? 0 : (nt < 4 ? 1 : 2);
  const float* bias = (seg == 0) ? b_vis : (seg == 1 ? b_q : b_lv);
  unsigned short* Y = (seg == 0) ? visb : (seg == 1 ? qout : lvout);
  float* statsraw   = (seg == 1) ? srq : srlv;
  const int nbase   = n0 - ((seg == 0) ? 0 : (seg == 1 ? 512 : 1024));
  const int Nseg    = (seg == 2) ? 768 : 512;

  float bb[4];
#pragma unroll
  for (int j = 0; j < 4; ++j) bb[j] = bias[nbase + wn + j * 16 + ln];
#pragma unroll
  for (int i = 0; i < 8; ++i)
#pragma unroll
    for (int j = 0; j < 4; ++j)
#pragma unroll
      for (int r = 0; r < 4; ++r) {
        float v = acc[i][j][r] + bb[j];
        if (seg == 0) v = gelu_f(v);
        acc[i][j][r] = v;
        size_t row = (size_t)(m0 + wm + i * 16 + quad * 4 + r);
        Y[row * Nseg + (nbase + wn + j * 16 + ln)] = f2bf(v);
      }
  if (seg != 0) {
    float* cs = (float*)As;
    cs[t] = 0.f;
    __syncthreads();
#pragma unroll
    for (int j = 0; j < 4; ++j) {
      float s = 0.f, s2 = 0.f;
#pragma unroll
      for (int i = 0; i < 8; ++i)
#pragma unroll
        for (int r = 0; r < 4; ++r) { float v = acc[i][j][r]; s += v; s2 += v * v; }
      s  += __shfl_xor(s, 16);  s  += __shfl_xor(s, 32);
      s2 += __shfl_xor(s2, 16); s2 += __shfl_xor(s2, 32);
      if (quad == 0) {
        int cl = wn + j * 16 + ln;
        atomicAdd(&cs[cl], s);
        atomicAdd(&cs[256 + cl], s2);
      }
    }
    __syncthreads();
    int bIdx = m0 >> 12;
    int col = t & 255;
    if (t < 256) atomicAdd(&statsraw[((size_t)bIdx * Nseg + nbase + col) * 2], cs[col]);
    else atomicAdd(&statsraw[((size_t)bIdx * Nseg + nbase + col) * 2 + 1], cs[256 + col]);
  }
}

// ---------------- fused sim + att-softmax + att@v + latt partial stats (MFMA) ----------------
__global__ __launch_bounds__(256) void simattv_kernel(
    const unsigned short* __restrict__ qraw, const float* __restrict__ srq,
    const float* __restrict__ kbuf, const float* __restrict__ vbuf,
    const float* __restrict__ lmask,
    unsigned short* __restrict__ simb, unsigned short* __restrict__ outb,
    float* __restrict__ pmx, float* __restrict__ psm)
{
  __shared__ __align__(16) unsigned short kThi[32][72];
  __shared__ __align__(16) unsigned short kTlo[32][72];
  __shared__ __align__(16) unsigned short vshi[64][40];
  __shared__ __align__(16) unsigned short vslo[64][40];
  __shared__ __align__(16) unsigned short pq[4][32][40];
  __shared__ float sm[64], srs[64], cb[32];
  __shared__ float wmax[4][32], wsum[4][32];

  const int qc = blockIdx.x, q0 = qc * 128, h = blockIdx.y, b = blockIdx.z;
  const int bh = b * 8 + h;
  const int t = threadIdx.x;
  const int wv = t >> 6, lane = t & 63, ln = lane & 15, quad = lane >> 4;
  const float scale = 0.04419417382415922f;  // 512^-0.5

  if (t < 64) {
    float s  = srq[(b * 512 + h * 64 + t) * 2];
    float s2 = srq[(b * 512 + h * 64 + t) * 2 + 1];
    float mean = s * (1.f / 4096.f);
    float var  = fmaxf(s2 * (1.f / 4096.f) - mean * mean, 0.f);
    sm[t]  = mean;
    srs[t] = rsqrtf(var + 1e-5f) * scale;
  }
  __syncthreads();

  const float* kb = kbuf + ((size_t)b * 512 + h * 64) * 32;
  const float* vb = vbuf + ((size_t)b * 512 + h * 64) * 32;
  for (int e = t; e < 2048; e += 256) {
    int d = e >> 5, n = e & 31;
    float kv = kb[e] * srs[d];
    unsigned short khi = f2bf(kv);
    kThi[n][d] = khi;
    kTlo[n][d] = f2bf(kv - bf2f(khi));
    float vv = vb[e];
    unsigned short vhi = f2bf(vv);
    vshi[d][n] = vhi;
    vslo[d][n] = f2bf(vv - bf2f(vhi));
  }
  if (t < 32) {
    float s = 0.f;
#pragma unroll 8
    for (int d = 0; d < 64; ++d) s += sm[d] * srs[d] * kb[d * 32 + t];
    cb[t] = 10000.f * (lmask[b * 32 + t] - 1.f) - s;
  }

  const unsigned short* qbase = qraw + ((size_t)(b * 4096) + q0 + wv * 32) * 512 + h * 64;
  bf16x8 qfr[2][2];
#pragma unroll
  for (int qf = 0; qf < 2; ++qf)
#pragma unroll
    for (int kf = 0; kf < 2; ++kf)
      qfr[qf][kf] = *(const bf16x8*)(qbase + (size_t)(qf * 16 + ln) * 512 + kf * 32 + quad * 8);
  __syncthreads();

  const f32x4 fz = {0.f, 0.f, 0.f, 0.f};
  f32x4 accS[2][2] = {{fz, fz}, {fz, fz}};
#pragma unroll
  for (int kf = 0; kf < 2; ++kf) {
#pragma unroll
    for (int nf = 0; nf < 2; ++nf) {
      bf16x8 kh = *(const bf16x8*)&kThi[nf * 16 + ln][kf * 32 + quad * 8];
      bf16x8 kl = *(const bf16x8*)&kTlo[nf * 16 + ln][kf * 32 + quad * 8];
#pragma unroll
      for (int qf = 0; qf < 2; ++qf) {
        accS[qf][nf] = __builtin_amdgcn_mfma_f32_16x16x32_bf16(qfr[qf][kf], kh, accS[qf][nf], 0, 0, 0);
        accS[qf][nf] = __builtin_amdgcn_mfma_f32_16x16x32_bf16(qfr[qf][kf], kl, accS[qf][nf], 0, 0, 0);
      }
    }
  }
  float cb0 = cb[ln], cb1 = cb[16 + ln];
#pragma unroll
  for (int qf = 0; qf < 2; ++qf)
#pragma unroll
    for (int r = 0; r < 4; ++r) {
      accS[qf][0][r] += cb0;
      accS[qf][1][r] += cb1;
    }
  {
    unsigned short* sgb = simb + ((size_t)bh * 4096 + q0 + wv * 32) * 32;
#pragma unroll
    for (int qf = 0; qf < 2; ++qf)
#pragma unroll
      for (int r = 0; r < 4; ++r) {
        size_t rowo = (size_t)(qf * 16 + quad * 4 + r) * 32;
        sgb[rowo + ln]      = f2bf(accS[qf][0][r]);
        sgb[rowo + 16 + ln] = f2bf(accS[qf][1][r]);
      }
  }
#pragma unroll
  for (int nf = 0; nf < 2; ++nf) {
    float m = accS[0][nf][0];
#pragma unroll
    for (int r = 1; r < 4; ++r) m = fmaxf(m, accS[0][nf][r]);
#pragma unroll
    for (int r = 0; r < 4; ++r) m = fmaxf(m, accS[1][nf][r]);
    m = fmaxf(m, __shfl_xor(m, 16));
    m = fmaxf(m, __shfl_xor(m, 32));
    float s = 0.f;
#pragma unroll
    for (int qf = 0; qf < 2; ++qf)
#pragma unroll
      for (int r = 0; r < 4; ++r) s += __expf(accS[qf][nf][r] - m);
    s += __shfl_xor(s, 16);
    s += __shfl_xor(s, 32);
    if (quad == 0) { wmax[wv][nf * 16 + ln] = m; wsum[wv][nf * 16 + ln] = s; }
  }
#pragma unroll
  for (int qf = 0; qf < 2; ++qf) {
#pragma unroll
    for (int r = 0; r < 4; ++r) {
      float a0 = accS[qf][0][r], a1 = accS[qf][1][r];
      float m = fmaxf(a0, a1);
      m = fmaxf(m, __shfl_xor(m, 1));
      m = fmaxf(m, __shfl_xor(m, 2));
      m = fmaxf(m, __shfl_xor(m, 4));
      m = fmaxf(m, __shfl_xor(m, 8));
      float e0 = __expf(a0 - m), e1 = __expf(a1 - m);
      float s = e0 + e1;
      s += __shfl_xor(s, 1);
      s += __shfl_xor(s, 2);
      s += __shfl_xor(s, 4);
      s += __shfl_xor(s, 8);
      float inv = 1.f / s;
      int row = qf * 16 + quad * 4 + r;
      pq[wv][row][ln]      = f2bf(e0 * inv);
      pq[wv][row][16 + ln] = f2bf(e1 * inv);
    }
  }
  __syncthreads();
  bf16x8 vfh[4], vfl[4];
#pragma unroll
  for (int mf = 0; mf < 4; ++mf) {
    vfh[mf] = *(const bf16x8*)&vshi[mf * 16 + ln][quad * 8];
    vfl[mf] = *(const bf16x8*)&vslo[mf * 16 + ln][quad * 8];
  }
#pragma unroll
  for (int nf = 0; nf < 2; ++nf) {
    bf16x8 pb = *(const bf16x8*)&pq[wv][nf * 16 + ln][quad * 8];
    f32x4 accO[4] = {fz, fz, fz, fz};
#pragma unroll
    for (int mf = 0; mf < 4; ++mf) {
      accO[mf] = __builtin_amdgcn_mfma_f32_16x16x32_bf16(vfh[mf], pb, accO[mf], 0, 0, 0);
      accO[mf] = __builtin_amdgcn_mfma_f32_16x16x32_bf16(vfl[mf], pb, accO[mf], 0, 0, 0);
    }
    unsigned short* op = outb + ((size_t)(b * 4096) + q0 + wv * 32 + nf * 16 + ln) * 512 + h * 64;
#pragma unroll
    for (int mf = 0; mf < 4; ++mf) {
      us4 o;
#pragma unroll
      for (int r = 0; r < 4; ++r) o[r] = f2bf(accO[mf][r]);
      *(us4*)(op + mf * 16 + quad * 4) = o;
    }
  }
  __syncthreads();
  if (t < 32) {
    float M = wmax[0][t], S = wsum[0][t];
#pragma unroll
    for (int g = 1; g < 4; ++g) {
      float m2 = wmax[g][t], s2 = wsum[g][t];
      if (m2 > M) { S = S * __expf(M - m2) + s2; M = m2; }
      else S += s2 * __expf(m2 - M);
    }
    pmx[((size_t)qc * 128 + bh) * 32 + t] = M;
    psm[((size_t)qc * 128 + bh) * 32 + t] = S;
  }
}

// ---------------- lang_out[b,h,c,n] += sum_q latt[n,q]*lvnorm[c,q] ----------------
__global__ __launch_bounds__(256) void langout_acc_kernel(
    const unsigned short* __restrict__ simb, const float* __restrict__ pmx,
    const float* __restrict__ psm, const unsigned short* __restrict__ lvraw,
    const float* __restrict__ srlv, float* __restrict__ lacc)
{
  __shared__ __align__(16) float pt[64][32];
  __shared__ __align__(16) float lvt[64][96];
  __shared__ float cm[96], cr[96], lm[32], li[32];
  int bh = blockIdx.x, b = bh >> 3, h = bh & 7;
  int qs0 = blockIdx.y * 512;
  int t = threadIdx.x;
  if (t < 96) {
    float s  = srlv[(b * 768 + h * 96 + t) * 2];
    float s2 = srlv[(b * 768 + h * 96 + t) * 2 + 1];
    float mean = s * (1.f / 4096.f);
    float var  = fmaxf(s2 * (1.f / 4096.f) - mean * mean, 0.f);
    cm[t] = mean;
    cr[t] = rsqrtf(var + 1e-5f);
  } else if (t >= 128 && t < 160) {
    int n = t - 128;
    float M = -1e30f, S = 0.f;
#pragma unroll 4
    for (int c = 0; c < 32; ++c) {
      float m2 = pmx[((size_t)c * 128 + bh) * 32 + n];
      float s2 = psm[((size_t)c * 128 + bh) * 32 + n];
      if (m2 > M) { S = S * __expf(M - m2) + s2; M = m2; }
      else S += s2 * __expf(m2 - M);
    }
    lm[n] = M;
    li[n] = 1.f / S;
  }
  __syncthreads();
  int n = t & 31, cg = t >> 5;
  float acc[12];
#pragma unroll
  for (int r = 0; r < 12; ++r) acc[r] = 0.f;
  for (int c0 = 0; c0 < 512; c0 += 64) {
    if (c0) __syncthreads();
#pragma unroll
    for (int i = 0; i < 8; ++i) {
      int e = t + 256 * i;
      int ql = e >> 5, nn = e & 31;
      float x = bf2f(simb[((size_t)bh * 4096 + qs0 + c0 + ql) * 32 + nn]);
      pt[ql][nn] = __expf(x - lm[nn]) * li[nn];
    }
#pragma unroll
    for (int i = 0; i < 24; ++i) {
      int e = t + 256 * i;
      int ql = e / 96, cc = e % 96;
      float v = bf2f(lvraw[((size_t)(b * 4096) + qs0 + c0 + ql) * 768 + h * 96 + cc]);
      lvt[ql][cc] = (v - cm[cc]) * cr[cc];
    }
    __syncthreads();
    for (int q = 0; q < 64; ++q) {
      float pv = pt[q][n];
      const f32x4* lp = (const f32x4*)&lvt[q][cg * 12];
      f32x4 a0 = lp[0], a1 = lp[1], a2 = lp[2];
      acc[0] += pv * a0[0]; acc[1] += pv * a0[1]; acc[2]  += pv * a0[2]; acc[3]  += pv * a0[3];
      acc[4] += pv * a1[0]; acc[5] += pv * a1[1]; acc[6]  += pv * a1[2]; acc[7]  += pv * a1[3];
      acc[8] += pv * a2[0]; acc[9] += pv * a2[1]; acc[10] += pv * a2[2]; acc[11] += pv * a2[3];
    }
  }
#pragma unroll
  for (int r = 0; r < 12; ++r)
    atomicAdd(&lacc[((size_t)b * 768 + h * 96 + cg * 12 + r) * 32 + n], acc[r]);
}

// ---------------- P = vis * inorm(Wout), stats inline from srw ----------------
__global__ __launch_bounds__(256) void prod_kernel(
    const unsigned short* __restrict__ visb, const unsigned short* __restrict__ wraw,
    const float* __restrict__ srw, unsigned short* __restrict__ P)
{
  size_t idx = ((size_t)blockIdx.x * 256 + threadIdx.x) * 8;
  int b = (int)(idx >> 21);
  int c = (int)(idx & 511);
  ushort8 vv = *(const ushort8*)&visb[idx];
  ushort8 wv = *(const ushort8*)&wraw[idx];
  ushort8 pv;
#pragma unroll
  for (int i = 0; i < 8; ++i) {
    float s  = srw[(b * 512 + c + i) * 2];
    float s2 = srw[(b * 512 + c + i) * 2 + 1];
    float mean = s * (1.f / 4096.f);
    float var  = fmaxf(s2 * (1.f / 4096.f) - mean * mean, 0.f);
    float rs   = rsqrtf(var + 1e-5f);
    pv[i] = f2bf(bf2f(vv[i]) * ((bf2f(wv[i]) - mean) * rs));
  }
  *(ushort8*)&P[idx] = pv;
}

// ---------------- langW conv + inorm over NL + *lang fuse (writes p2 directly) ----------------
__global__ __launch_bounds__(256) void langW_kernel(
    const float* __restrict__ lacc, const float* __restrict__ w,
    const float* __restrict__ bias, const float* __restrict__ lmask,
    const float* __restrict__ lang, float* __restrict__ p2)
{
  int b = blockIdx.x, og = blockIdx.y;
  int ol = threadIdx.x >> 5, n = threadIdx.x & 31;
  int o = og * 8 + ol;
  const float* ab = lacc + (size_t)b * 768 * 32 + n;
  const float* wr = w + (size_t)o * 768;
  float s = 0.f;
#pragma unroll 4
  for (int i = 0; i < 768; ++i) s += wr[i] * ab[(size_t)i * 32];
  float y = s * lmask[b * 32 + n] + bias[o];
  float m = y;
#pragma unroll
  for (int off = 16; off >= 1; off >>= 1) m += __shfl_xor(m, off);
  m *= (1.f / 32.f);
  float d = y - m;
  float vv = d * d;
#pragma unroll
  for (int off = 16; off >= 1; off >>= 1) vv += __shfl_xor(vv, off);
  vv *= (1.f / 32.f);
  size_t idx = ((size_t)b * 768 + o) * 32 + n;
  p2[idx] = lang[idx] * (d * rsqrtf(vv + 1e-5f));
}

// ---------------- langmm conv + gelu, store transposed (B,NL,CL) f32 ----------------
__global__ __launch_bounds__(256) void langmm_kernel(
    const float* __restrict__ p2, const float* __restrict__ w,
    const float* __restrict__ bias, float* __restrict__ out1)
{
  int b = blockIdx.x, og = blockIdx.y;
  int ol = threadIdx.x >> 5, n = threadIdx.x & 31;
  int o = og * 8 + ol;
  const float* pb = p2 + (size_t)b * 768 * 32 + n;
  const float* wr = w + (size_t)o * 768;
  float s = 0.f;
#pragma unroll 4
  for (int i = 0; i < 768; ++i) s += wr[i] * pb[(size_t)i * 32];
  s = gelu_f(s + bias[o]);
  __shared__ float tile[8][32];
  tile[ol][n] = s;
  __syncthreads();
  int nn = threadIdx.x >> 3, cl = threadIdx.x & 7;
  out1[((size_t)b * 32 + nn) * 768 + og * 8 + cl] = tile[cl][nn];
}

// ---------------- launch ----------------
extern "C" void kernel_launch(void* const* d_in, const int* in_sizes, int n_in,
                              void* d_out, int out_size, void* d_ws, size_t ws_size,
                              hipStream_t stream)
{
  (void)in_sizes; (void)n_in; (void)out_size; (void)ws_size;
  const float* x       = (const float*)d_in[0];
  const float* l       = (const float*)d_in[1];
  const float* lmask   = (const float*)d_in[2];
  const float* w_vis   = (const float*)d_in[3];
  const float* b_vis   = (const float*)d_in[4];
  const float* w_langp = (const float*)d_in[5];
  const float* b_langp = (const float*)d_in[6];
  const float* w_q     = (const float*)d_in[7];
  const float* b_q     = (const float*)d_in[8];
  const float* w_k     = (const float*)d_in[9];
  const float* b_k     = (const float*)d_in[10];
  const float* w_v     = (const float*)d_in[11];
  const float* b_v     = (const float*)d_in[12];
  const float* w_lv    = (const float*)d_in[13];
  const float* b_lv    = (const float*)d_in[14];
  const float* w_W     = (const float*)d_in[15];
  const float* b_W     = (const float*)d_in[16];
  const float* w_langW = (const float*)d_in[17];
  const float* b_langW = (const float*)d_in[18];
  const float* w_mm    = (const float*)d_in[19];
  const float* b_mm    = (const float*)d_in[20];
  const float* w_langmm= (const float*)d_in[21];
  const float* b_langmm= (const float*)d_in[22];

  char* ws = (char*)d_ws;
  float* srq  = (float*)(ws + OFF_SRQ);
  float* srlv = (float*)(ws + OFF_SRLV);
  float* srw  = (float*)(ws + OFF_SRW);
  float* lacc = (float*)(ws + OFF_LACC);
  float* kbuf = (float*)(ws + OFF_KBUF);
  float* vbuf = (float*)(ws + OFF_VBUF);
  float* lang = (float*)(ws + OFF_LANG);
  float* p2   = (float*)(ws + OFF_P2);
  float* pmx  = (float*)(ws + OFF_PMX);
  float* psm  = (float*)(ws + OFF_PSM);
  unsigned short* wb    = (unsigned short*)(ws + OFF_WB);
  unsigned short* wbW   = wb + 917504;
  unsigned short* wbmm  = wb + 1179648;
  unsigned short* qraw  = (unsigned short*)(ws + OFF_Q);
  unsigned short* lvraw = (unsigned short*)(ws + OFF_LV);
  unsigned short* wraw  = (unsigned short*)(ws + OFF_LV);
  unsigned short* simb  = (unsigned short*)(ws + OFF_SIMB);
  float* out0 = (float*)d_out;
  float* out1 = out0 + (size_t)16 * 4096 * 512;
  unsigned short* visb = (unsigned short*)d_out;                 // [0,64MB)
  unsigned short* xb   = (unsigned short*)d_out + 33554432;      // [64,128MB)

  // prep: converts + small convs + zero of atomic accumulators
  prep_kernel<<<21112, 256, 0, stream>>>(x, w_vis, w_q, w_lv, w_W, w_mm, xb, wb,
                                         l, w_langp, b_langp, w_k, b_k, w_v, b_v,
                                         lmask, lang, kbuf, vbuf, (float*)ws);

  // fused vis|q|lv GEMM: 256^2 tile, A (xb) read once, n-fastest + XCD swizzle
  gemm_fused3<<<256 * 7, 512, 0, stream>>>(xb, wb, b_vis, b_q, b_lv,
                                           visb, qraw, lvraw, srq, srlv);

  // attention (fused sim+softmax+PV+latt partials, MFMA; q-norm stats inline)
  simattv_kernel<<<dim3(32, 8, 16), 256, 0, stream>>>(qraw, srq, kbuf, vbuf, lmask, simb, qraw, pmx, psm);
  langout_acc_kernel<<<dim3(128, 8), 256, 0, stream>>>(simb, pmx, psm, lvraw, srlv, lacc);

  // visual output path
  gemm_bt<false, true,  false><<<256 * 2, 512, 0, stream>>>(qraw, wbW, b_W, wraw, srw, 512, 512, 2);
  prod_kernel<<<16384, 256, 0, stream>>>(visb, wraw, srw, qraw);
  gemm_bt<true,  false, true ><<<256 * 2, 512, 0, stream>>>(qraw, wbmm, b_mm, out0, nullptr, 512, 512, 2);

  // language output path
  langW_kernel<<<dim3(16, 96), 256, 0, stream>>>(lacc, w_langW, b_langW, lmask, lang, p2);
  langmm_kernel<<<dim3(16, 96), 256, 0, stream>>>(p2, w_langmm, b_langmm, out1);
}